// Round 6
// baseline (360.244 us; speedup 1.0000x reference)
//
#include <hip/hip_runtime.h>
#include <hip/hip_bf16.h>

// Problem dims
#define BB 32
#define LL 256
#define KC 50
#define SS 16
#define DD 128
#define NH 4
#define CC 128
#define VV 50000
#define NNN 100000
#define NUU 50000
#define NSS 5000

typedef __attribute__((ext_vector_type(8))) short bf16x8;
typedef __attribute__((ext_vector_type(8))) unsigned short u16x8;
typedef __attribute__((ext_vector_type(4))) float f32x4;

__device__ __forceinline__ float dot4(float4 a, float4 b){
  return a.x*b.x + a.y*b.y + a.z*b.z + a.w*b.w;
}

__device__ __forceinline__ unsigned short f2bf(float f){
  union { float f; unsigned int u; } v; v.f = f;
  unsigned int r = (v.u + 0x7FFFu + ((v.u >> 16) & 1u)) >> 16;
  return (unsigned short)r;
}
__device__ __forceinline__ float bf2f(unsigned short s){
  union { unsigned int u; float f; } v; v.u = ((unsigned int)s) << 16;
  return v.f;
}

// ---------------------------------------------------------------------------
// 0) unified weight prep: conv wb3/4/5, GRU wgb, word-attn wab, meta-MHA wmh
__global__ __launch_bounds__(256) void k_prep(
    const float* __restrict__ w3, const float* __restrict__ w4,
    const float* __restrict__ w5,
    const float* __restrict__ wih0, const float* __restrict__ whh0,
    const float* __restrict__ wih1, const float* __restrict__ whh1,
    const float* __restrict__ in_w, const float* __restrict__ out_w,
    const float* __restrict__ inw0, const float* __restrict__ outw0,
    const float* __restrict__ inw1, const float* __restrict__ outw1,
    unsigned short* __restrict__ wb3, unsigned short* __restrict__ wb4,
    unsigned short* __restrict__ wb5, unsigned short* __restrict__ wgb,
    unsigned short* __restrict__ wab, unsigned short* __restrict__ wmh){
  int e = blockIdx.x*256 + threadIdx.x;
  if (e < CC*DD*3){ int c=e/(DD*3), rm=e%(DD*3), d=rm/3, jj=rm%3;
    wb3[((size_t)jj*CC + c)*DD + d] = f2bf(w3[e]); }
  if (e < CC*DD*4){ int c=e/(DD*4), rm=e%(DD*4), d=rm/4, jj=rm%4;
    wb4[((size_t)jj*CC + c)*DD + d] = f2bf(w4[e]); }
  if (e < CC*DD*5){ int c=e/(DD*5), rm=e%(DD*5), d=rm/5, jj=rm%5;
    wb5[((size_t)jj*CC + c)*DD + d] = f2bf(w5[e]); }
  if (e < 384*DD){
    wgb[e]          = f2bf(wih0[e]);
    wgb[49152 + e]  = f2bf(whh0[e]);
    wgb[98304 + e]  = f2bf(wih1[e]);
    wgb[147456 + e] = f2bf(whh1[e]);
    wab[e]          = f2bf(in_w[e]);
  }
  if (e >= 384*DD && e < 512*DD) wab[e] = f2bf(out_w[e - 384*DD]);
  if (e < 512*DD){
    float s0 = (e < 384*DD) ? inw0[e] : outw0[e - 384*DD];
    float s1 = (e < 384*DD) ? inw1[e] : outw1[e - 384*DD];
    wmh[e]                 = f2bf(s0);
    wmh[(size_t)512*DD + e] = f2bf(s1);
  }
}

// ---------------------------------------------------------------------------
// FUSED 1: gru [0,128) | projkv [128,1378) | qh [1378,1506)
// All three depend only on k_prep; horizontal fusion lets latency-bound
// gru/qh blocks fill CUs idle during projkv's memory stalls.
#define F1_GRU 128
#define F1_PKV 1250
#define PST 136   // projkv A-stage row stride (shorts)
#define TST 72    // projkv transpose scratch row stride (shorts)
#define CPAD 136
#define GSTR 392
__global__ __launch_bounds__(256) void k_fused1(
    // projkv
    const float* __restrict__ news, const unsigned short* __restrict__ wkvb,
    const float* __restrict__ in_b,
    unsigned short* __restrict__ nK, unsigned short* __restrict__ nV,
    // qh
    const float* __restrict__ word_table, const int* __restrict__ widx,
    const unsigned short* __restrict__ wqb, float* __restrict__ qh_out,
    // gru
    const float* __restrict__ user_table, const float* __restrict__ source_table,
    const int* __restrict__ news_ids, const int* __restrict__ nsn_src,
    const int* __restrict__ nsn_end, const int* __restrict__ nun_usr,
    const int* __restrict__ nun_end, const unsigned short* __restrict__ wgb,
    const float* __restrict__ bih0, const float* __restrict__ bhh0,
    const float* __restrict__ bih1, const float* __restrict__ bhh1,
    float* __restrict__ enc){
  __shared__ __align__(16) char smem[38912];
  const int blk = blockIdx.x;
  const int tid = threadIdx.x;
  const int wave = tid >> 6, lane = tid & 63, l15 = lane & 15, quad = lane >> 4;

  if (blk < F1_GRU){
    // ---------------- GRU ----------------
    auto xs = (unsigned short(*)[CPAD])(smem);          // 16x136 shorts
    auto hs = (unsigned short(*)[CPAD])(smem + 4352);
    auto hf = (float(*)[128])(smem + 8704);
    auto gi = (float(*)[GSTR])(smem + 12800);
    auto gh = (float(*)[GSTR])(smem + 25344);
    const int m  = blk >> 6;
    const int b  = (blk >> 1) & 31;
    const int s0 = (blk & 1) * 8;
    const unsigned short* Wih = wgb + (size_t)m*2*384*DD;
    const unsigned short* Whh = Wih + 384*DD;
    const float* bih = m ? bih1 : bih0;
    const float* bhh = m ? bhh1 : bhh0;
    for (int i=tid;i<16*CPAD;i+=256){ (&xs[0][0])[i]=0; (&hs[0][0])[i]=0; }
    for (int i=tid;i<8*128;i+=256) (&hf[0][0])[i]=0.f;
    __syncthreads();
    for (int t=0;t<3;t++){
      {
        int s = tid >> 5, j = tid & 31;
        int row; const float* tab;
        if (t==0){ row = news_ids[b]; tab = news; }
        else if (t==1){ row = m ? nun_usr[b*SS+s0+s] : nsn_src[b*SS+s0+s];
                        tab = m ? user_table : source_table; }
        else { row = m ? nun_end[b*SS+s0+s] : nsn_end[b*SS+s0+s]; tab = news; }
        float4 v = ((const float4*)(tab + (size_t)row*DD))[j];
        unsigned short* dp = &xs[s][j*4];
        dp[0]=f2bf(v.x); dp[1]=f2bf(v.y); dp[2]=f2bf(v.z); dp[3]=f2bf(v.w);
      }
      __syncthreads();
      bf16x8 ax[4], ah[4];
      #pragma unroll
      for (int ks=0;ks<4;ks++){
        ax[ks] = *(const bf16x8*)&xs[l15][ks*32+quad*8];
        ah[ks] = *(const bf16x8*)&hs[l15][ks*32+quad*8];
      }
      #pragma unroll
      for (int nt=0;nt<6;nt++){
        const int n0 = wave*96 + nt*16;
        f32x4 ga = {0.f,0.f,0.f,0.f}, ha = {0.f,0.f,0.f,0.f};
        #pragma unroll
        for (int ks=0;ks<4;ks++){
          bf16x8 bi = *(const bf16x8*)(Wih + (size_t)(n0+l15)*DD + ks*32+quad*8);
          ga = __builtin_amdgcn_mfma_f32_16x16x32_bf16(ax[ks], bi, ga, 0,0,0);
          bf16x8 bh = *(const bf16x8*)(Whh + (size_t)(n0+l15)*DD + ks*32+quad*8);
          ha = __builtin_amdgcn_mfma_f32_16x16x32_bf16(ah[ks], bh, ha, 0,0,0);
        }
        if (quad < 2){
          #pragma unroll
          for (int r=0;r<4;r++){
            gi[quad*4+r][n0+l15] = ga[r];
            gh[quad*4+r][n0+l15] = ha[r];
          }
        }
      }
      __syncthreads();
      #pragma unroll
      for (int k=0;k<4;k++){
        int it = tid + k*256;
        int s = it >> 7, g = it & 127;
        float rr = 1.f/(1.f+__expf(-(gi[s][g] + gh[s][g] + bih[g] + bhh[g])));
        float zz = 1.f/(1.f+__expf(-(gi[s][128+g] + gh[s][128+g] + bih[128+g] + bhh[128+g])));
        float nn = tanhf(gi[s][256+g] + bih[256+g] + rr*(gh[s][256+g] + bhh[256+g]));
        float hnew = (1.f-zz)*nn + zz*hf[s][g];
        hf[s][g] = hnew;
        hs[s][g] = f2bf(hnew);
      }
      __syncthreads();
    }
    {
      int s = tid >> 5, j = tid & 31;
      float4 v = ((const float4*)hf[s])[j];
      ((float4*)(enc + (((size_t)m*BB + b)*SS + (s0+s))*DD))[j] = v;
    }
  } else if (blk < F1_GRU + F1_PKV){
    // ---------------- projkv (BM=80, R5-proven body) ----------------
    unsigned short* As = (unsigned short*)smem;            // 80*PST
    unsigned short* Tw = (unsigned short*)(smem + 21760);  // 4*16*TST
    const int r0 = (blk - F1_GRU) * 80;
    const int cw = wave * 64;
    bf16x8 wfr[4][4];
    #pragma unroll
    for (int nt=0; nt<4; nt++)
      #pragma unroll
      for (int ks=0; ks<4; ks++)
        wfr[nt][ks] = *(const bf16x8*)(wkvb + (size_t)(cw + nt*16 + l15)*DD + ks*32 + quad*8);
    float4 bv[4];
    #pragma unroll
    for (int nt=0; nt<4; nt++)
      bv[nt] = *(const float4*)(in_b + 128 + cw + nt*16 + quad*4);
    for (int i = tid; i < 80*32; i += 256){
      int row = i >> 5, j = i & 31;
      float4 v = ((const float4*)(news + (size_t)(r0 + row)*DD))[j];
      unsigned short* d = As + row*PST + j*4;
      d[0]=f2bf(v.x); d[1]=f2bf(v.y); d[2]=f2bf(v.z); d[3]=f2bf(v.w);
    }
    __syncthreads();
    unsigned short* outp = (wave < 2) ? nK : nV;
    const int cwo = (wave & 1) * 64;
    unsigned short* tw = Tw + wave*16*TST;
    const int rr = lane >> 4;
    const int cc = lane & 15;
    #pragma unroll
    for (int mt=0; mt<5; mt++){
      bf16x8 afr[4];
      #pragma unroll
      for (int ks=0; ks<4; ks++)
        afr[ks] = *(const bf16x8*)(As + (mt*16 + l15)*PST + ks*32 + quad*8);
      f32x4 acc[4];
      #pragma unroll
      for (int nt=0; nt<4; nt++) acc[nt] = (f32x4){0.f,0.f,0.f,0.f};
      #pragma unroll
      for (int ks=0; ks<4; ks++)
        #pragma unroll
        for (int nt=0; nt<4; nt++)
          acc[nt] = __builtin_amdgcn_mfma_f32_16x16x32_bf16(wfr[nt][ks], afr[ks], acc[nt], 0,0,0);
      #pragma unroll
      for (int nt=0; nt<4; nt++){
        unsigned short pk[4];
        pk[0] = f2bf(acc[nt][0] + bv[nt].x);
        pk[1] = f2bf(acc[nt][1] + bv[nt].y);
        pk[2] = f2bf(acc[nt][2] + bv[nt].z);
        pk[3] = f2bf(acc[nt][3] + bv[nt].w);
        *(unsigned long long*)(tw + l15*TST + nt*16 + quad*4) = *(const unsigned long long*)pk;
      }
      const int gr0 = r0 + mt*16;
      #pragma unroll
      for (int s=0; s<4; s++){
        unsigned long long v = *(const unsigned long long*)(tw + (s*4 + rr)*TST + cc*4);
        *(unsigned long long*)(outp + (size_t)(gr0 + s*4 + rr)*DD + cwo + cc*4) = v;
      }
    }
  } else {
    // ---------------- qh: 4 waves x 16-row tiles ----------------
    const int p0 = ((blk - F1_GRU - F1_PKV)*4 + wave) * 16;
    const int row = widx[p0 + l15];
    const float* src = word_table + (size_t)row*DD + quad*8;
    bf16x8 afr[4];
    #pragma unroll
    for (int ks=0; ks<4; ks++){
      float4 v0 = *(const float4*)(src + ks*32);
      float4 v1 = *(const float4*)(src + ks*32 + 4);
      bf16x8 a;
      a[0]=(short)f2bf(v0.x); a[1]=(short)f2bf(v0.y); a[2]=(short)f2bf(v0.z); a[3]=(short)f2bf(v0.w);
      a[4]=(short)f2bf(v1.x); a[5]=(short)f2bf(v1.y); a[6]=(short)f2bf(v1.z); a[7]=(short)f2bf(v1.w);
      afr[ks] = a;
    }
    #pragma unroll
    for (int nt=0; nt<8; nt++){
      const int n0 = nt*16;
      bf16x8 bfr[4];
      #pragma unroll
      for (int ks=0; ks<4; ks++)
        bfr[ks] = *(const bf16x8*)(wqb + (size_t)(n0+l15)*DD + ks*32 + quad*8);
      const float bias = in_b[n0 + l15];
      f32x4 acc = {0.f,0.f,0.f,0.f};
      #pragma unroll
      for (int ks=0; ks<4; ks++)
        acc = __builtin_amdgcn_mfma_f32_16x16x32_bf16(afr[ks], bfr[ks], acc, 0,0,0);
      #pragma unroll
      for (int r=0;r<4;r++){
        int m = quad*4 + r;
        qh_out[(size_t)(p0+m)*DD + n0 + l15] = acc[r] + bias;
      }
    }
  }
}

// ---------------------------------------------------------------------------
// 3) per-(b,l) attention, one wave per token; writes o as bf16.
__global__ __launch_bounds__(64) void k_attn(
    const float* __restrict__ qh, const unsigned short* __restrict__ nK,
    const unsigned short* __restrict__ nV, const int* __restrict__ ctx_ids,
    unsigned short* __restrict__ o_out){
  const int p = blockIdx.x;
  const int lane = threadIdx.x;
  const int r = lane >> 4;
  const int g = lane & 15;
  const int h = g >> 2;
  __shared__ int ids[52];
  __shared__ float sc[NH][52];
  if (lane < KC) ids[lane] = ctx_ids[(size_t)p*KC + lane];
  float qv[8];
  {
    const float4* qp = (const float4*)(qh + (size_t)p*DD + g*8);
    float4 q0 = qp[0], q1 = qp[1];
    qv[0]=q0.x; qv[1]=q0.y; qv[2]=q0.z; qv[3]=q0.w;
    qv[4]=q1.x; qv[5]=q1.y; qv[6]=q1.z; qv[7]=q1.w;
  }
  __syncthreads();
  for (int kb=0; kb<13; kb++){
    int k2 = kb*4 + r;
    int row = ids[(k2 < KC) ? k2 : 0];
    u16x8 kv = *(const u16x8*)(nK + (size_t)row*DD + g*8);
    float pr = 0.f;
    #pragma unroll
    for (int j=0;j<8;j++) pr += qv[j]*bf2f(kv[j]);
    pr += __shfl_xor(pr, 1, 64);
    pr += __shfl_xor(pr, 2, 64);
    if ((g & 3) == 0 && k2 < KC) sc[h][k2] = pr;
  }
  __syncthreads();
  {
    const int hh = lane >> 4, kc = lane & 15;
    const float scale = 0.17677669529663687f;
    float mx = -1e30f;
    #pragma unroll
    for (int q4=0;q4<4;q4++){ int k2=kc+q4*16; if (k2<KC) mx = fmaxf(mx, sc[hh][k2]); }
    mx = fmaxf(mx, __shfl_xor(mx, 1, 64));
    mx = fmaxf(mx, __shfl_xor(mx, 2, 64));
    mx = fmaxf(mx, __shfl_xor(mx, 4, 64));
    mx = fmaxf(mx, __shfl_xor(mx, 8, 64));
    float sm = 0.f;
    float ev[4];
    #pragma unroll
    for (int q4=0;q4<4;q4++){
      int k2=kc+q4*16;
      ev[q4] = (k2<KC) ? __expf((sc[hh][k2]-mx)*scale) : 0.f;
      sm += ev[q4];
    }
    sm += __shfl_xor(sm, 1, 64);
    sm += __shfl_xor(sm, 2, 64);
    sm += __shfl_xor(sm, 4, 64);
    sm += __shfl_xor(sm, 8, 64);
    float inv = 1.f/sm;
    #pragma unroll
    for (int q4=0;q4<4;q4++){ int k2=kc+q4*16; if (k2<KC) sc[hh][k2] = ev[q4]*inv; }
  }
  __syncthreads();
  float acc[8];
  #pragma unroll
  for (int j=0;j<8;j++) acc[j]=0.f;
  for (int kb=0; kb<13; kb++){
    int k2 = kb*4 + r;
    int row = ids[(k2 < KC) ? k2 : 0];
    float w = (k2 < KC) ? sc[h][k2] : 0.f;
    u16x8 vv = *(const u16x8*)(nV + (size_t)row*DD + g*8);
    #pragma unroll
    for (int j=0;j<8;j++) acc[j] += w*bf2f(vv[j]);
  }
  #pragma unroll
  for (int j=0;j<8;j++){
    acc[j] += __shfl_xor(acc[j], 16, 64);
    acc[j] += __shfl_xor(acc[j], 32, 64);
  }
  if (r == 0){
    u16x8 o;
    #pragma unroll
    for (int j=0;j<8;j++) o[j] = f2bf(acc[j]);
    *(u16x8*)(o_out + (size_t)p*DD + g*8) = o;
  }
}

// ---------------------------------------------------------------------------
// FUSED 2: wo [0,128) | metamha [128,192)
// wo depends on attn; metamha depends on gru (fused1) — independent of wo.
#define MPAD 136
__global__ __launch_bounds__(256) void k_fused2(
    // wo
    const unsigned short* __restrict__ o_attn, const int* __restrict__ widx,
    const unsigned short* __restrict__ wob, const float* __restrict__ out_b,
    unsigned short* __restrict__ doc,
    // metamha
    const float* __restrict__ enc, const unsigned short* __restrict__ wmh,
    const float* __restrict__ inb0, const float* __restrict__ outb0,
    const float* __restrict__ lng0, const float* __restrict__ lnb0,
    const float* __restrict__ inb1, const float* __restrict__ outb1,
    const float* __restrict__ lng1, const float* __restrict__ lnb1,
    float* __restrict__ meta_e){
  __shared__ __align__(16) char smem[39296];
  const int blk = blockIdx.x;
  const int tid = threadIdx.x;
  const int wave = tid >> 6, lane = tid & 63, l15 = lane & 15, quad = lane >> 4;

  if (blk < 128){
    // ---------------- wo: 4 waves x 16-row tiles ----------------
    const int p0 = (blk*4 + wave) * 16;
    bf16x8 afr[4];
    #pragma unroll
    for (int ks=0; ks<4; ks++)
      afr[ks] = *(const bf16x8*)(o_attn + (size_t)(p0+l15)*DD + ks*32 + quad*8);
    int msk[4];
    #pragma unroll
    for (int r=0;r<4;r++) msk[r] = widx[p0 + quad*4 + r];
    #pragma unroll
    for (int nt=0; nt<8; nt++){
      const int n0 = nt*16;
      bf16x8 bfr[4];
      #pragma unroll
      for (int ks=0; ks<4; ks++)
        bfr[ks] = *(const bf16x8*)(wob + (size_t)(n0+l15)*DD + ks*32 + quad*8);
      const float bias = out_b[n0 + l15];
      f32x4 acc = {0.f,0.f,0.f,0.f};
      #pragma unroll
      for (int ks=0; ks<4; ks++)
        acc = __builtin_amdgcn_mfma_f32_16x16x32_bf16(afr[ks], bfr[ks], acc, 0,0,0);
      #pragma unroll
      for (int r=0;r<4;r++){
        int m = quad*4 + r;
        doc[(size_t)(p0+m)*DD + n0 + l15] = (msk[r] == 0) ? (unsigned short)0
                                                          : f2bf(acc[r] + bias);
      }
    }
  } else {
    // ---------------- metamha ----------------
    auto ebf = (unsigned short(*)[MPAD])(smem);
    auto qb  = (unsigned short(*)[MPAD])(smem + 4352);
    auto kb  = (unsigned short(*)[MPAD])(smem + 8704);
    auto ob  = (unsigned short(*)[MPAD])(smem + 13056);
    auto vf  = (float(*)[128])(smem + 17408);
    auto er  = (float(*)[132])(smem + 25600);
    auto at  = (float(*)[16][16])(smem + 34048);
    float* mu = (float*)(smem + 38144);
    float* rs = (float*)(smem + 38208);
    auto part = (float(*)[128])(smem + 38272);
    const int mb = blk - 128;
    const int m = mb >> 5;
    const int b = mb & 31;
    const unsigned short* W = wmh + (size_t)m*512*DD;
    const float* in_b  = m ? inb1 : inb0;
    const float* outb  = m ? outb1 : outb0;
    const float* lng   = m ? lng1 : lng0;
    const float* lnb   = m ? lnb1 : lnb0;
    const float* esrc = enc + ((size_t)m*BB + b)*SS*DD;
    for (int i = tid; i < 16*32; i += 256){
      int s = i >> 5, j = i & 31;
      float4 v = ((const float4*)esrc)[i];
      ((float4*)er[s])[j] = v;
      unsigned short* dp = &ebf[s][j*4];
      dp[0]=f2bf(v.x); dp[1]=f2bf(v.y); dp[2]=f2bf(v.z); dp[3]=f2bf(v.w);
    }
    __syncthreads();
    {
      bf16x8 ax[4];
      #pragma unroll
      for (int ks=0;ks<4;ks++) ax[ks] = *(const bf16x8*)&ebf[l15][ks*32+quad*8];
      #pragma unroll
      for (int nt=0; nt<6; nt++){
        const int n0 = wave*96 + nt*16;
        f32x4 acc = {0.f,0.f,0.f,0.f};
        #pragma unroll
        for (int ks=0;ks<4;ks++){
          bf16x8 bw = *(const bf16x8*)(W + (size_t)(n0+l15)*DD + ks*32+quad*8);
          acc = __builtin_amdgcn_mfma_f32_16x16x32_bf16(ax[ks], bw, acc, 0,0,0);
        }
        const float bias = in_b[n0+l15];
        const int col = n0 + l15;
        #pragma unroll
        for (int r=0;r<4;r++){
          int row = quad*4+r;
          float val = acc[r] + bias;
          if (n0 < 128)      qb[row][col]       = f2bf(val);
          else if (n0 < 256) kb[row][col-128]   = f2bf(val);
          else               vf[row][col-256]   = val;
        }
      }
    }
    __syncthreads();
    {
      const int h = wave;
      bf16x8 aq = *(const bf16x8*)&qb[l15][h*32 + quad*8];
      bf16x8 ak = *(const bf16x8*)&kb[l15][h*32 + quad*8];
      f32x4 z = {0.f,0.f,0.f,0.f};
      f32x4 acc = __builtin_amdgcn_mfma_f32_16x16x32_bf16(aq, ak, z, 0,0,0);
      #pragma unroll
      for (int r=0;r<4;r++)
        at[h][quad*4+r][l15] = acc[r] * 0.17677669529663687f;
    }
    __syncthreads();
    if (tid < 64){
      int h = tid>>4, qi = tid&15;
      float mx=-1e30f;
      #pragma unroll
      for (int ki=0;ki<16;ki++) mx = fmaxf(mx, at[h][qi][ki]);
      float sm=0.f;
      float ee[16];
      #pragma unroll
      for (int ki=0;ki<16;ki++){ ee[ki]=__expf(at[h][qi][ki]-mx); sm+=ee[ki]; }
      float inv=1.f/sm;
      #pragma unroll
      for (int ki=0;ki<16;ki++) at[h][qi][ki]=ee[ki]*inv;
    }
    __syncthreads();
    {
      int c = tid & 127, h = c >> 5;
      int sBase = (tid >> 7) * 8;
      #pragma unroll
      for (int s=0;s<8;s++){
        float acc=0.f;
        #pragma unroll
        for (int ki=0;ki<16;ki++) acc += at[h][sBase+s][ki]*vf[ki][c];
        ob[sBase+s][c] = f2bf(acc);
      }
    }
    __syncthreads();
    {
      bf16x8 ao[4];
      #pragma unroll
      for (int ks=0;ks<4;ks++) ao[ks] = *(const bf16x8*)&ob[l15][ks*32+quad*8];
      #pragma unroll
      for (int nt=0; nt<2; nt++){
        const int n0 = wave*32 + nt*16;
        f32x4 acc = {0.f,0.f,0.f,0.f};
        #pragma unroll
        for (int ks=0;ks<4;ks++){
          bf16x8 bw = *(const bf16x8*)(W + (size_t)(384 + n0+l15)*DD + ks*32+quad*8);
          acc = __builtin_amdgcn_mfma_f32_16x16x32_bf16(ao[ks], bw, acc, 0,0,0);
        }
        const float bias = outb[n0+l15];
        const int col = n0 + l15;
        #pragma unroll
        for (int r=0;r<4;r++){
          int row = quad*4 + r;
          er[row][col] += acc[r] + bias;
        }
      }
    }
    __syncthreads();
    {
      int row = tid >> 4, i = tid & 15;
      const float* yr = &er[row][i*8];
      float s1=0.f, s2=0.f;
      #pragma unroll
      for (int j2=0;j2<8;j2++){ float y=yr[j2]; s1+=y; s2+=y*y; }
      #pragma unroll
      for (int msk2=1; msk2<16; msk2<<=1){
        s1 += __shfl_xor(s1, msk2, 64);
        s2 += __shfl_xor(s2, msk2, 64);
      }
      if (i==0){
        float mean = s1*(1.f/128.f);
        mu[row]=mean;
        rs[row]=rsqrtf(s2*(1.f/128.f) - mean*mean + 1e-5f);
      }
    }
    __syncthreads();
    {
      int c = tid & 127, half = tid >> 7;
      float g = lng[c], bb2 = lnb[c];
      float acc=0.f;
      #pragma unroll
      for (int s=0;s<8;s++){
        int ss = half*8+s;
        acc += (er[ss][c]-mu[ss])*rs[ss]*g + bb2;
      }
      part[half][c]=acc;
    }
    __syncthreads();
    if (tid < 128)
      meta_e[((size_t)m*BB+b)*DD + tid] = (part[0][tid]+part[1][tid]) * (1.f/16.f);
  }
}

// ---------------------------------------------------------------------------
// 6) conv as MFMA GEMM + fused max-over-t (doc already bf16: staging = copy)
#define CROWS 68
__global__ __launch_bounds__(256) void k_conv(
    const unsigned short* __restrict__ doc, const unsigned short* __restrict__ wb3,
    const unsigned short* __restrict__ wb4, const unsigned short* __restrict__ wb5,
    float* __restrict__ convp){
  __shared__ __align__(16) char smem[CROWS*CPAD*2];
  unsigned short* ds = (unsigned short*)smem;
  float* smf = (float*)smem;
  const int blk = blockIdx.x;
  const int chunk = blk & 3;
  const int j = (blk >> 2) % 3;
  const int b = blk / 12;
  const int kk = 3 + j;
  const int T = LL - kk + 1;
  const int t0 = chunk * 64;
  const int nrows = 64 + kk - 1;
  const unsigned short* wb = (j==0) ? wb3 : (j==1) ? wb4 : wb5;
  const int tid = threadIdx.x;
  for (int i = tid; i < nrows*16; i += 256){
    int row = i >> 4, q8 = i & 15;
    int gt = t0 + row;
    u16x8 v = (u16x8){0,0,0,0,0,0,0,0};
    if (gt < LL) v = *(const u16x8*)(doc + ((size_t)b*LL + gt)*DD + q8*8);
    *(u16x8*)(ds + row*CPAD + q8*8) = v;
  }
  __syncthreads();
  const int wave = tid >> 6;
  const int lane = tid & 63;
  const int l15  = lane & 15;
  const int quad = lane >> 4;
  f32x4 acc[8];
  #pragma unroll
  for (int nt=0;nt<8;nt++) acc[nt] = (f32x4){0.f,0.f,0.f,0.f};
  for (int jj=0; jj<kk; jj++){
    #pragma unroll
    for (int ks=0; ks<4; ks++){
      bf16x8 af = *(const bf16x8*)(ds + (wave*16 + l15 + jj)*CPAD + ks*32 + quad*8);
      #pragma unroll
      for (int nt=0; nt<8; nt++){
        bf16x8 bf = *(const bf16x8*)(wb + ((size_t)jj*CC + nt*16 + l15)*DD + ks*32 + quad*8);
        acc[nt] = __builtin_amdgcn_mfma_f32_16x16x32_bf16(af, bf, acc[nt], 0,0,0);
      }
    }
  }
  __syncthreads();
  #pragma unroll
  for (int nt=0; nt<8; nt++){
    float mx = -1e30f;
    #pragma unroll
    for (int r=0;r<4;r++){
      int t = t0 + wave*16 + quad*4 + r;
      mx = fmaxf(mx, (t < T) ? acc[nt][r] : -1e30f);
    }
    mx = fmaxf(mx, __shfl_xor(mx, 16, 64));
    mx = fmaxf(mx, __shfl_xor(mx, 32, 64));
    if (quad == 0) smf[wave*128 + nt*16 + l15] = mx;
  }
  __syncthreads();
  if (tid < 128){
    float m4 = fmaxf(fmaxf(smf[tid], smf[128+tid]), fmaxf(smf[256+tid], smf[384+tid]));
    convp[(((size_t)b*3 + j)*4 + chunk)*CC + tid] = m4;
  }
}

// ---------------------------------------------------------------------------
// 9) pool-reduce + fc + meta gate + classifier; block per b
__global__ __launch_bounds__(128) void k_final(
    const float* __restrict__ convp,
    const float* __restrict__ cb3, const float* __restrict__ cb4,
    const float* __restrict__ cb5,
    const float* __restrict__ fc_w, const float* __restrict__ fc_b,
    const float* __restrict__ meta_e,
    const float* __restrict__ mp_w1, const float* __restrict__ mp_b1,
    const float* __restrict__ mp_w2, const float* __restrict__ mp_b2,
    const float* __restrict__ cls_w1, const float* __restrict__ cls_b1,
    const float* __restrict__ cls_w2, const float* __restrict__ cls_b2,
    float* __restrict__ out){
  const int b = blockIdx.x;
  const int c = threadIdx.x;
  __shared__ float pooled[384];
  __shared__ float comb[256];
  __shared__ float hcls[128];
  __shared__ float tt[2][64];
  __shared__ float wsc[2];
  for (int idx=c; idx<384; idx+=128){
    int j = idx >> 7, cc2 = idx & 127;
    const float* base = convp + (((size_t)b*3 + j)*4)*CC + cc2;
    float mx = -1e30f;
    for (int ci=0;ci<4;ci++) mx = fmaxf(mx, base[ci*CC]);
    const float* cb = (j==0)?cb3:(j==1)?cb4:cb5;
    pooled[idx] = fmaxf(mx + cb[cc2], 0.f);
  }
  __syncthreads();
  {
    float acc = fc_b[c];
    const float* wr = fc_w + (size_t)c*384;
    for (int i=0;i<384;i++) acc += pooled[i]*wr[i];
    comb[c] = acc;
  }
  if (c < 64){
    for (int m=0;m<2;m++){
      const float* ev = meta_e + ((size_t)m*BB+b)*DD;
      float acc = mp_b1[c];
      const float* wr = mp_w1 + (size_t)c*DD;
      for (int i=0;i<DD;i++) acc += ev[i]*wr[i];
      tt[m][c] = tanhf(acc);
    }
  }
  __syncthreads();
  if (c == 0){
    float s0 = mp_b2[0], s1 = mp_b2[0];
    for (int j=0;j<64;j++){ s0 += tt[0][j]*mp_w2[j]; s1 += tt[1][j]*mp_w2[j]; }
    float mx = fmaxf(s0,s1);
    float e0 = __expf(s0-mx), e1 = __expf(s1-mx);
    wsc[0] = e0/(e0+e1); wsc[1] = e1/(e0+e1);
  }
  __syncthreads();
  comb[128+c] = wsc[0]*meta_e[((size_t)b)*DD + c]
              + wsc[1]*meta_e[((size_t)(BB+b))*DD + c];
  __syncthreads();
  {
    float acc = cls_b1[c];
    const float* wr = cls_w1 + (size_t)c*256;
    for (int i=0;i<256;i++) acc += comb[i]*wr[i];
    hcls[c] = fmaxf(acc, 0.f);
  }
  __syncthreads();
  if (c < 2){
    float acc = cls_b2[c];
    const float* wr = cls_w2 + (size_t)c*DD;
    for (int i=0;i<DD;i++) acc += hcls[i]*wr[i];
    out[b*2 + c] = acc;
  }
}

// ---------------------------------------------------------------------------
extern "C" void kernel_launch(void* const* d_in, const int* in_sizes, int n_in,
                              void* d_out, int out_size, void* d_ws, size_t ws_size,
                              hipStream_t stream){
  const int* news_ids = (const int*)d_in[0];
  const int* nwi      = (const int*)d_in[1];
  const int* ctx_ids  = (const int*)d_in[2];
  const int* nsn_src  = (const int*)d_in[3];
  const int* nsn_end  = (const int*)d_in[4];
  const int* nun_usr  = (const int*)d_in[5];
  const int* nun_end  = (const int*)d_in[6];
  const float* word_table   = (const float*)d_in[7];
  const float* news_table   = (const float*)d_in[8];
  const float* user_table   = (const float*)d_in[9];
  const float* source_table = (const float*)d_in[10];
  const float* wa_in_w  = (const float*)d_in[11];
  const float* wa_in_b  = (const float*)d_in[12];
  const float* wa_out_w = (const float*)d_in[13];
  const float* wa_out_b = (const float*)d_in[14];
  const float* conv_w3 = (const float*)d_in[15];
  const float* conv_b3 = (const float*)d_in[16];
  const float* conv_w4 = (const float*)d_in[17];
  const float* conv_b4 = (const float*)d_in[18];
  const float* conv_w5 = (const float*)d_in[19];
  const float* conv_b5 = (const float*)d_in[20];
  const float* fc_w = (const float*)d_in[21];
  const float* fc_b = (const float*)d_in[22];
  const float* wih0 = (const float*)d_in[23];
  const float* whh0 = (const float*)d_in[24];
  const float* bih0 = (const float*)d_in[25];
  const float* bhh0 = (const float*)d_in[26];
  const float* inw0 = (const float*)d_in[27];
  const float* inb0 = (const float*)d_in[28];
  const float* outw0 = (const float*)d_in[29];
  const float* outb0 = (const float*)d_in[30];
  const float* lng0 = (const float*)d_in[31];
  const float* lnb0 = (const float*)d_in[32];
  const float* wih1 = (const float*)d_in[33];
  const float* whh1 = (const float*)d_in[34];
  const float* bih1 = (const float*)d_in[35];
  const float* bhh1 = (const float*)d_in[36];
  const float* inw1 = (const float*)d_in[37];
  const float* inb1 = (const float*)d_in[38];
  const float* outw1 = (const float*)d_in[39];
  const float* outb1 = (const float*)d_in[40];
  const float* lng1 = (const float*)d_in[41];
  const float* lnb1 = (const float*)d_in[42];
  const float* mp_w1 = (const float*)d_in[43];
  const float* mp_b1 = (const float*)d_in[44];
  const float* mp_w2 = (const float*)d_in[45];
  const float* mp_b2 = (const float*)d_in[46];
  const float* cls_w1 = (const float*)d_in[47];
  const float* cls_b1 = (const float*)d_in[48];
  const float* cls_w2 = (const float*)d_in[49];
  const float* cls_b2 = (const float*)d_in[50];

  // workspace layout
  char* wsb = (char*)d_ws;
  unsigned short* nK = (unsigned short*)wsb;                 // NNN*DD bf16
  unsigned short* nV = nK + (size_t)NNN*DD;                  // NNN*DD bf16
  unsigned short* wb3 = nV + (size_t)NNN*DD;
  unsigned short* wb4 = wb3 + (size_t)CC*DD*3;
  unsigned short* wb5 = wb4 + (size_t)CC*DD*4;
  unsigned short* wgb = wb5 + (size_t)CC*DD*5;               // 4*384*128 bf16
  unsigned short* wab = wgb + (size_t)4*384*DD;              // 512*128 bf16
  unsigned short* wmh = wab + (size_t)512*DD;                // 2*512*128 bf16
  float* qh     = (float*)(wmh + (size_t)2*512*DD);
  unsigned short* o_at = (unsigned short*)(qh + (size_t)BB*LL*DD);   // bf16
  unsigned short* doc  = (unsigned short*)((float*)o_at + (size_t)BB*LL*DD); // bf16
  float* convp  = (float*)doc + (size_t)BB*LL*DD;
  float* enc    = convp + BB*3*4*CC;
  float* meta_e = enc + (size_t)2*BB*SS*DD;
  const size_t need_bytes = (size_t)((char*)(meta_e + 2*BB*DD) - wsb);
  if (ws_size < need_bytes) return;

  const unsigned short* wqb  = wab;                   // rows 0..127 (wq)
  const unsigned short* wkvb = wab + (size_t)128*DD;  // rows 128..383 (wk;wv)
  const unsigned short* wob  = wab + (size_t)384*DD;  // out_w

  k_prep<<<dim3(320), dim3(256), 0, stream>>>(conv_w3, conv_w4, conv_w5,
      wih0, whh0, wih1, whh1, wa_in_w, wa_out_w,
      inw0, outw0, inw1, outw1,
      wb3, wb4, wb5, wgb, wab, wmh);
  k_fused1<<<dim3(F1_GRU + F1_PKV + 128), dim3(256), 0, stream>>>(
      news_table, wkvb, wa_in_b, nK, nV,
      word_table, nwi, wqb, qh,
      user_table, source_table, news_ids, nsn_src, nsn_end, nun_usr, nun_end,
      wgb, bih0, bhh0, bih1, bhh1, enc);
  k_attn<<<dim3(BB*LL), dim3(64), 0, stream>>>(qh, nK, nV, ctx_ids, o_at);
  k_fused2<<<dim3(192), dim3(256), 0, stream>>>(o_at, nwi, wob, wa_out_b, doc,
      enc, wmh, inb0, outb0, lng0, lnb0, inb1, outb1, lng1, lnb1, meta_e);
  k_conv<<<dim3(BB*3*4), dim3(256), 0, stream>>>(doc, wb3, wb4, wb5, convp);
  k_final<<<dim3(BB), dim3(128), 0, stream>>>(convp, conv_b3, conv_b4, conv_b5,
      fc_w, fc_b, meta_e, mp_w1, mp_b1, mp_w2, mp_b2,
      cls_w1, cls_b1, cls_w2, cls_b2, (float*)d_out);
}

// Round 8
// 352.587 us; speedup vs baseline: 1.0217x; 1.0217x over previous
//
#include <hip/hip_runtime.h>
#include <hip/hip_bf16.h>

// Problem dims
#define BB 32
#define LL 256
#define KC 50
#define SS 16
#define DD 128
#define NH 4
#define CC 128
#define VV 50000
#define NNN 100000
#define NUU 50000
#define NSS 5000

typedef __attribute__((ext_vector_type(8))) short bf16x8;
typedef __attribute__((ext_vector_type(8))) unsigned short u16x8;
typedef __attribute__((ext_vector_type(4))) float f32x4;

__device__ __forceinline__ float dot4(float4 a, float4 b){
  return a.x*b.x + a.y*b.y + a.z*b.z + a.w*b.w;
}

__device__ __forceinline__ unsigned short f2bf(float f){
  union { float f; unsigned int u; } v; v.f = f;
  unsigned int r = (v.u + 0x7FFFu + ((v.u >> 16) & 1u)) >> 16;
  return (unsigned short)r;
}
__device__ __forceinline__ float bf2f(unsigned short s){
  union { unsigned int u; float f; } v; v.u = ((unsigned int)s) << 16;
  return v.f;
}

// ---------------------------------------------------------------------------
// 0) unified weight prep: conv wb3/4/5, GRU wgb, word-attn wab, meta-MHA wmh
__global__ __launch_bounds__(256) void k_prep(
    const float* __restrict__ w3, const float* __restrict__ w4,
    const float* __restrict__ w5,
    const float* __restrict__ wih0, const float* __restrict__ whh0,
    const float* __restrict__ wih1, const float* __restrict__ whh1,
    const float* __restrict__ in_w, const float* __restrict__ out_w,
    const float* __restrict__ inw0, const float* __restrict__ outw0,
    const float* __restrict__ inw1, const float* __restrict__ outw1,
    unsigned short* __restrict__ wb3, unsigned short* __restrict__ wb4,
    unsigned short* __restrict__ wb5, unsigned short* __restrict__ wgb,
    unsigned short* __restrict__ wab, unsigned short* __restrict__ wmh){
  int e = blockIdx.x*256 + threadIdx.x;
  if (e < CC*DD*3){ int c=e/(DD*3), rm=e%(DD*3), d=rm/3, jj=rm%3;
    wb3[((size_t)jj*CC + c)*DD + d] = f2bf(w3[e]); }
  if (e < CC*DD*4){ int c=e/(DD*4), rm=e%(DD*4), d=rm/4, jj=rm%4;
    wb4[((size_t)jj*CC + c)*DD + d] = f2bf(w4[e]); }
  if (e < CC*DD*5){ int c=e/(DD*5), rm=e%(DD*5), d=rm/5, jj=rm%5;
    wb5[((size_t)jj*CC + c)*DD + d] = f2bf(w5[e]); }
  if (e < 384*DD){
    wgb[e]          = f2bf(wih0[e]);
    wgb[49152 + e]  = f2bf(whh0[e]);
    wgb[98304 + e]  = f2bf(wih1[e]);
    wgb[147456 + e] = f2bf(whh1[e]);
    wab[e]          = f2bf(in_w[e]);
  }
  if (e >= 384*DD && e < 512*DD) wab[e] = f2bf(out_w[e - 384*DD]);
  if (e < 512*DD){
    float s0 = (e < 384*DD) ? inw0[e] : outw0[e - 384*DD];
    float s1 = (e < 384*DD) ? inw1[e] : outw1[e - 384*DD];
    wmh[e]                 = f2bf(s0);
    wmh[(size_t)512*DD + e] = f2bf(s1);
  }
}

// ---------------------------------------------------------------------------
// FUSED PQ: projkv [0,1250) | qh [1250,1378)
// Lean branches only (gru's 140-VGPR branch evicted — R6 lesson: per-branch
// worst-case VGPR throttles ALL blocks). projkv restructured to 2 passes of
// 32 cols (wfr[2][4] = 32 VGPR instead of 64) targeting <=102 VGPR ->
// 5 waves/SIMD; LDS 26.9 KB -> 5 blocks/CU.
#define PQ_PKV 1250
#define PST 136   // A-stage row stride (shorts)
#define TST2 40   // transpose scratch row stride (shorts), 32 data + 8 pad
__global__ __launch_bounds__(256) void k_pq(
    const float* __restrict__ news, const unsigned short* __restrict__ wkvb,
    const float* __restrict__ in_b,
    unsigned short* __restrict__ nK, unsigned short* __restrict__ nV,
    const float* __restrict__ word_table, const int* __restrict__ widx,
    const unsigned short* __restrict__ wqb, float* __restrict__ qh_out){
  __shared__ __align__(16) unsigned short As[80*PST];   // 21760 B
  __shared__ __align__(16) unsigned short Tw[4*16*TST2]; // 5120 B
  const int blk = blockIdx.x;
  const int tid = threadIdx.x;
  const int wave = tid >> 6, lane = tid & 63, l15 = lane & 15, quad = lane >> 4;

  if (blk < PQ_PKV){
    // ---------------- projkv (BM=80, 2-pass cols) ----------------
    const int r0 = blk * 80;
    // stage A: 80 rows x 128 f32 -> bf16 LDS, fully coalesced
    for (int i = tid; i < 80*32; i += 256){
      int row = i >> 5, j = i & 31;
      float4 v = ((const float4*)(news + (size_t)(r0 + row)*DD))[j];
      unsigned short* d = As + row*PST + j*4;
      d[0]=f2bf(v.x); d[1]=f2bf(v.y); d[2]=f2bf(v.z); d[3]=f2bf(v.w);
    }
    __syncthreads();
    unsigned short* outp = (wave < 2) ? nK : nV;
    unsigned short* tw = Tw + wave*16*TST2;
    const int rr8 = lane >> 3, cc8 = lane & 7;
    for (int half=0; half<2; half++){
      const int c0 = wave*64 + half*32;   // col base in [wk;wv] (0..255)
      const int cm = c0 & 127;            // col base within nK/nV row
      bf16x8 wfr[2][4];
      #pragma unroll
      for (int nt=0; nt<2; nt++)
        #pragma unroll
        for (int ks=0; ks<4; ks++)
          wfr[nt][ks] = *(const bf16x8*)(wkvb + (size_t)(c0 + nt*16 + l15)*DD + ks*32 + quad*8);
      float4 bv0 = *(const float4*)(in_b + 128 + c0 + quad*4);
      float4 bv1 = *(const float4*)(in_b + 128 + c0 + 16 + quad*4);
      #pragma unroll
      for (int mt=0; mt<5; mt++){
        bf16x8 afr[4];
        #pragma unroll
        for (int ks=0; ks<4; ks++)
          afr[ks] = *(const bf16x8*)(As + (mt*16 + l15)*PST + ks*32 + quad*8);
        f32x4 a0 = {0.f,0.f,0.f,0.f}, a1 = {0.f,0.f,0.f,0.f};
        #pragma unroll
        for (int ks=0; ks<4; ks++){
          a0 = __builtin_amdgcn_mfma_f32_16x16x32_bf16(wfr[0][ks], afr[ks], a0, 0,0,0);
          a1 = __builtin_amdgcn_mfma_f32_16x16x32_bf16(wfr[1][ks], afr[ks], a1, 0,0,0);
        }
        // lane holds cols c0+{0,16}+quad*4..+3 of news row (r0+mt*16+l15)
        {
          unsigned short pk[4];
          pk[0]=f2bf(a0[0]+bv0.x); pk[1]=f2bf(a0[1]+bv0.y);
          pk[2]=f2bf(a0[2]+bv0.z); pk[3]=f2bf(a0[3]+bv0.w);
          *(unsigned long long*)(tw + l15*TST2 + quad*4) = *(const unsigned long long*)pk;
          pk[0]=f2bf(a1[0]+bv1.x); pk[1]=f2bf(a1[1]+bv1.y);
          pk[2]=f2bf(a1[2]+bv1.z); pk[3]=f2bf(a1[3]+bv1.w);
          *(unsigned long long*)(tw + l15*TST2 + 16 + quad*4) = *(const unsigned long long*)pk;
        }
        // wave-private transpose readback -> 64B-contiguous stores, 8 rows/instr
        const int gr0 = r0 + mt*16;
        #pragma unroll
        for (int s=0; s<2; s++){
          unsigned long long v = *(const unsigned long long*)(tw + (s*8+rr8)*TST2 + cc8*4);
          *(unsigned long long*)(outp + (size_t)(gr0 + s*8 + rr8)*DD + cm + cc8*4) = v;
        }
      }
    }
  } else {
    // ---------------- qh: 4 waves x 16-row tiles ----------------
    const int p0 = ((blk - PQ_PKV)*4 + wave) * 16;
    const int row = widx[p0 + l15];
    const float* src = word_table + (size_t)row*DD + quad*8;
    bf16x8 afr[4];
    #pragma unroll
    for (int ks=0; ks<4; ks++){
      float4 v0 = *(const float4*)(src + ks*32);
      float4 v1 = *(const float4*)(src + ks*32 + 4);
      bf16x8 a;
      a[0]=(short)f2bf(v0.x); a[1]=(short)f2bf(v0.y); a[2]=(short)f2bf(v0.z); a[3]=(short)f2bf(v0.w);
      a[4]=(short)f2bf(v1.x); a[5]=(short)f2bf(v1.y); a[6]=(short)f2bf(v1.z); a[7]=(short)f2bf(v1.w);
      afr[ks] = a;
    }
    #pragma unroll
    for (int nt=0; nt<8; nt++){
      const int n0 = nt*16;
      bf16x8 bfr[4];
      #pragma unroll
      for (int ks=0; ks<4; ks++)
        bfr[ks] = *(const bf16x8*)(wqb + (size_t)(n0+l15)*DD + ks*32 + quad*8);
      const float bias = in_b[n0 + l15];
      f32x4 acc = {0.f,0.f,0.f,0.f};
      #pragma unroll
      for (int ks=0; ks<4; ks++)
        acc = __builtin_amdgcn_mfma_f32_16x16x32_bf16(afr[ks], bfr[ks], acc, 0,0,0);
      #pragma unroll
      for (int r=0;r<4;r++){
        int m = quad*4 + r;
        qh_out[(size_t)(p0+m)*DD + n0 + l15] = acc[r] + bias;
      }
    }
  }
}

// ---------------------------------------------------------------------------
// 7) GRU via MFMA; standalone (its 140-VGPR body must not tax other branches)
#define CPAD 136
#define GSTR 392
__global__ __launch_bounds__(256) void k_gru(
    const float* __restrict__ news_table, const float* __restrict__ user_table,
    const float* __restrict__ source_table,
    const int* __restrict__ news_ids, const int* __restrict__ nsn_src,
    const int* __restrict__ nsn_end, const int* __restrict__ nun_usr,
    const int* __restrict__ nun_end,
    const unsigned short* __restrict__ wgb,
    const float* __restrict__ bih0, const float* __restrict__ bhh0,
    const float* __restrict__ bih1, const float* __restrict__ bhh1,
    float* __restrict__ enc){
  __shared__ __align__(16) unsigned short xs[16][CPAD];
  __shared__ __align__(16) unsigned short hs[16][CPAD];
  __shared__ float hf[8][128];
  __shared__ float gi[8][GSTR];
  __shared__ float gh[8][GSTR];
  const int blk = blockIdx.x;
  const int m  = blk >> 6;
  const int b  = (blk >> 1) & 31;
  const int s0 = (blk & 1) * 8;
  const int tid = threadIdx.x;
  const int wave = tid >> 6, lane = tid & 63, l15 = lane & 15, quad = lane >> 4;
  const unsigned short* Wih = wgb + (size_t)m*2*384*DD;
  const unsigned short* Whh = Wih + 384*DD;
  const float* bih = m ? bih1 : bih0;
  const float* bhh = m ? bhh1 : bhh0;
  for (int i=tid;i<16*CPAD;i+=256){ (&xs[0][0])[i]=0; (&hs[0][0])[i]=0; }
  for (int i=tid;i<8*128;i+=256) (&hf[0][0])[i]=0.f;
  __syncthreads();
  for (int t=0;t<3;t++){
    {
      int s = tid >> 5, j = tid & 31;
      int row; const float* tab;
      if (t==0){ row = news_ids[b]; tab = news_table; }
      else if (t==1){ row = m ? nun_usr[b*SS+s0+s] : nsn_src[b*SS+s0+s];
                      tab = m ? user_table : source_table; }
      else { row = m ? nun_end[b*SS+s0+s] : nsn_end[b*SS+s0+s]; tab = news_table; }
      float4 v = ((const float4*)(tab + (size_t)row*DD))[j];
      unsigned short* dp = &xs[s][j*4];
      dp[0]=f2bf(v.x); dp[1]=f2bf(v.y); dp[2]=f2bf(v.z); dp[3]=f2bf(v.w);
    }
    __syncthreads();
    bf16x8 ax[4], ah[4];
    #pragma unroll
    for (int ks=0;ks<4;ks++){
      ax[ks] = *(const bf16x8*)&xs[l15][ks*32+quad*8];
      ah[ks] = *(const bf16x8*)&hs[l15][ks*32+quad*8];
    }
    #pragma unroll
    for (int nt=0;nt<6;nt++){
      const int n0 = wave*96 + nt*16;
      f32x4 ga = {0.f,0.f,0.f,0.f}, ha = {0.f,0.f,0.f,0.f};
      #pragma unroll
      for (int ks=0;ks<4;ks++){
        bf16x8 bi = *(const bf16x8*)(Wih + (size_t)(n0+l15)*DD + ks*32+quad*8);
        ga = __builtin_amdgcn_mfma_f32_16x16x32_bf16(ax[ks], bi, ga, 0,0,0);
        bf16x8 bh = *(const bf16x8*)(Whh + (size_t)(n0+l15)*DD + ks*32+quad*8);
        ha = __builtin_amdgcn_mfma_f32_16x16x32_bf16(ah[ks], bh, ha, 0,0,0);
      }
      if (quad < 2){
        #pragma unroll
        for (int r=0;r<4;r++){
          gi[quad*4+r][n0+l15] = ga[r];
          gh[quad*4+r][n0+l15] = ha[r];
        }
      }
    }
    __syncthreads();
    #pragma unroll
    for (int k=0;k<4;k++){
      int it = tid + k*256;
      int s = it >> 7, g = it & 127;
      float rr = 1.f/(1.f+__expf(-(gi[s][g] + gh[s][g] + bih[g] + bhh[g])));
      float zz = 1.f/(1.f+__expf(-(gi[s][128+g] + gh[s][128+g] + bih[128+g] + bhh[128+g])));
      float nn = tanhf(gi[s][256+g] + bih[256+g] + rr*(gh[s][256+g] + bhh[256+g]));
      float hnew = (1.f-zz)*nn + zz*hf[s][g];
      hf[s][g] = hnew;
      hs[s][g] = f2bf(hnew);
    }
    __syncthreads();
  }
  {
    int s = tid >> 5, j = tid & 31;
    float4 v = ((const float4*)hf[s])[j];
    ((float4*)(enc + (((size_t)m*BB + b)*SS + (s0+s))*DD))[j] = v;
  }
}

// ---------------------------------------------------------------------------
// 3) per-(b,l) attention, one wave per token; writes o as bf16.
__global__ __launch_bounds__(64) void k_attn(
    const float* __restrict__ qh, const unsigned short* __restrict__ nK,
    const unsigned short* __restrict__ nV, const int* __restrict__ ctx_ids,
    unsigned short* __restrict__ o_out){
  const int p = blockIdx.x;
  const int lane = threadIdx.x;
  const int r = lane >> 4;
  const int g = lane & 15;
  const int h = g >> 2;
  __shared__ int ids[52];
  __shared__ float sc[NH][52];
  if (lane < KC) ids[lane] = ctx_ids[(size_t)p*KC + lane];
  float qv[8];
  {
    const float4* qp = (const float4*)(qh + (size_t)p*DD + g*8);
    float4 q0 = qp[0], q1 = qp[1];
    qv[0]=q0.x; qv[1]=q0.y; qv[2]=q0.z; qv[3]=q0.w;
    qv[4]=q1.x; qv[5]=q1.y; qv[6]=q1.z; qv[7]=q1.w;
  }
  __syncthreads();
  for (int kb=0; kb<13; kb++){
    int k2 = kb*4 + r;
    int row = ids[(k2 < KC) ? k2 : 0];
    u16x8 kv = *(const u16x8*)(nK + (size_t)row*DD + g*8);
    float pr = 0.f;
    #pragma unroll
    for (int j=0;j<8;j++) pr += qv[j]*bf2f(kv[j]);
    pr += __shfl_xor(pr, 1, 64);
    pr += __shfl_xor(pr, 2, 64);
    if ((g & 3) == 0 && k2 < KC) sc[h][k2] = pr;
  }
  __syncthreads();
  {
    const int hh = lane >> 4, kc = lane & 15;
    const float scale = 0.17677669529663687f;
    float mx = -1e30f;
    #pragma unroll
    for (int q4=0;q4<4;q4++){ int k2=kc+q4*16; if (k2<KC) mx = fmaxf(mx, sc[hh][k2]); }
    mx = fmaxf(mx, __shfl_xor(mx, 1, 64));
    mx = fmaxf(mx, __shfl_xor(mx, 2, 64));
    mx = fmaxf(mx, __shfl_xor(mx, 4, 64));
    mx = fmaxf(mx, __shfl_xor(mx, 8, 64));
    float sm = 0.f;
    float ev[4];
    #pragma unroll
    for (int q4=0;q4<4;q4++){
      int k2=kc+q4*16;
      ev[q4] = (k2<KC) ? __expf((sc[hh][k2]-mx)*scale) : 0.f;
      sm += ev[q4];
    }
    sm += __shfl_xor(sm, 1, 64);
    sm += __shfl_xor(sm, 2, 64);
    sm += __shfl_xor(sm, 4, 64);
    sm += __shfl_xor(sm, 8, 64);
    float inv = 1.f/sm;
    #pragma unroll
    for (int q4=0;q4<4;q4++){ int k2=kc+q4*16; if (k2<KC) sc[hh][k2] = ev[q4]*inv; }
  }
  __syncthreads();
  float acc[8];
  #pragma unroll
  for (int j=0;j<8;j++) acc[j]=0.f;
  for (int kb=0; kb<13; kb++){
    int k2 = kb*4 + r;
    int row = ids[(k2 < KC) ? k2 : 0];
    float w = (k2 < KC) ? sc[h][k2] : 0.f;
    u16x8 vv = *(const u16x8*)(nV + (size_t)row*DD + g*8);
    #pragma unroll
    for (int j=0;j<8;j++) acc[j] += w*bf2f(vv[j]);
  }
  #pragma unroll
  for (int j=0;j<8;j++){
    acc[j] += __shfl_xor(acc[j], 16, 64);
    acc[j] += __shfl_xor(acc[j], 32, 64);
  }
  if (r == 0){
    u16x8 o;
    #pragma unroll
    for (int j=0;j<8;j++) o[j] = f2bf(acc[j]);
    *(u16x8*)(o_out + (size_t)p*DD + g*8) = o;
  }
}

// ---------------------------------------------------------------------------
// FUSED 2: wo [0,128) | metamha [128,192)
#define MPAD 136
__global__ __launch_bounds__(256) void k_fused2(
    const unsigned short* __restrict__ o_attn, const int* __restrict__ widx,
    const unsigned short* __restrict__ wob, const float* __restrict__ out_b,
    unsigned short* __restrict__ doc,
    const float* __restrict__ enc, const unsigned short* __restrict__ wmh,
    const float* __restrict__ inb0, const float* __restrict__ outb0,
    const float* __restrict__ lng0, const float* __restrict__ lnb0,
    const float* __restrict__ inb1, const float* __restrict__ outb1,
    const float* __restrict__ lng1, const float* __restrict__ lnb1,
    float* __restrict__ meta_e){
  __shared__ __align__(16) char smem[39296];
  const int blk = blockIdx.x;
  const int tid = threadIdx.x;
  const int wave = tid >> 6, lane = tid & 63, l15 = lane & 15, quad = lane >> 4;

  if (blk < 128){
    const int p0 = (blk*4 + wave) * 16;
    bf16x8 afr[4];
    #pragma unroll
    for (int ks=0; ks<4; ks++)
      afr[ks] = *(const bf16x8*)(o_attn + (size_t)(p0+l15)*DD + ks*32 + quad*8);
    int msk[4];
    #pragma unroll
    for (int r=0;r<4;r++) msk[r] = widx[p0 + quad*4 + r];
    #pragma unroll
    for (int nt=0; nt<8; nt++){
      const int n0 = nt*16;
      bf16x8 bfr[4];
      #pragma unroll
      for (int ks=0; ks<4; ks++)
        bfr[ks] = *(const bf16x8*)(wob + (size_t)(n0+l15)*DD + ks*32 + quad*8);
      const float bias = out_b[n0 + l15];
      f32x4 acc = {0.f,0.f,0.f,0.f};
      #pragma unroll
      for (int ks=0; ks<4; ks++)
        acc = __builtin_amdgcn_mfma_f32_16x16x32_bf16(afr[ks], bfr[ks], acc, 0,0,0);
      #pragma unroll
      for (int r=0;r<4;r++){
        int m = quad*4 + r;
        doc[(size_t)(p0+m)*DD + n0 + l15] = (msk[r] == 0) ? (unsigned short)0
                                                          : f2bf(acc[r] + bias);
      }
    }
  } else {
    auto ebf = (unsigned short(*)[MPAD])(smem);
    auto qb  = (unsigned short(*)[MPAD])(smem + 4352);
    auto kb  = (unsigned short(*)[MPAD])(smem + 8704);
    auto ob  = (unsigned short(*)[MPAD])(smem + 13056);
    auto vf  = (float(*)[128])(smem + 17408);
    auto er  = (float(*)[132])(smem + 25600);
    auto at  = (float(*)[16][16])(smem + 34048);
    float* mu = (float*)(smem + 38144);
    float* rs = (float*)(smem + 38208);
    auto part = (float(*)[128])(smem + 38272);
    const int mb = blk - 128;
    const int m = mb >> 5;
    const int b = mb & 31;
    const unsigned short* W = wmh + (size_t)m*512*DD;
    const float* in_b  = m ? inb1 : inb0;
    const float* outb  = m ? outb1 : outb0;
    const float* lng   = m ? lng1 : lng0;
    const float* lnb   = m ? lnb1 : lnb0;
    const float* esrc = enc + ((size_t)m*BB + b)*SS*DD;
    for (int i = tid; i < 16*32; i += 256){
      int s = i >> 5, j = i & 31;
      float4 v = ((const float4*)esrc)[i];
      ((float4*)er[s])[j] = v;
      unsigned short* dp = &ebf[s][j*4];
      dp[0]=f2bf(v.x); dp[1]=f2bf(v.y); dp[2]=f2bf(v.z); dp[3]=f2bf(v.w);
    }
    __syncthreads();
    {
      bf16x8 ax[4];
      #pragma unroll
      for (int ks=0;ks<4;ks++) ax[ks] = *(const bf16x8*)&ebf[l15][ks*32+quad*8];
      #pragma unroll
      for (int nt=0; nt<6; nt++){
        const int n0 = wave*96 + nt*16;
        f32x4 acc = {0.f,0.f,0.f,0.f};
        #pragma unroll
        for (int ks=0;ks<4;ks++){
          bf16x8 bw = *(const bf16x8*)(W + (size_t)(n0+l15)*DD + ks*32+quad*8);
          acc = __builtin_amdgcn_mfma_f32_16x16x32_bf16(ax[ks], bw, acc, 0,0,0);
        }
        const float bias = in_b[n0+l15];
        const int col = n0 + l15;
        #pragma unroll
        for (int r=0;r<4;r++){
          int row = quad*4+r;
          float val = acc[r] + bias;
          if (n0 < 128)      qb[row][col]       = f2bf(val);
          else if (n0 < 256) kb[row][col-128]   = f2bf(val);
          else               vf[row][col-256]   = val;
        }
      }
    }
    __syncthreads();
    {
      const int h = wave;
      bf16x8 aq = *(const bf16x8*)&qb[l15][h*32 + quad*8];
      bf16x8 ak = *(const bf16x8*)&kb[l15][h*32 + quad*8];
      f32x4 z = {0.f,0.f,0.f,0.f};
      f32x4 acc = __builtin_amdgcn_mfma_f32_16x16x32_bf16(aq, ak, z, 0,0,0);
      #pragma unroll
      for (int r=0;r<4;r++)
        at[h][quad*4+r][l15] = acc[r] * 0.17677669529663687f;
    }
    __syncthreads();
    if (tid < 64){
      int h = tid>>4, qi = tid&15;
      float mx=-1e30f;
      #pragma unroll
      for (int ki=0;ki<16;ki++) mx = fmaxf(mx, at[h][qi][ki]);
      float sm=0.f;
      float ee[16];
      #pragma unroll
      for (int ki=0;ki<16;ki++){ ee[ki]=__expf(at[h][qi][ki]-mx); sm+=ee[ki]; }
      float inv=1.f/sm;
      #pragma unroll
      for (int ki=0;ki<16;ki++) at[h][qi][ki]=ee[ki]*inv;
    }
    __syncthreads();
    {
      int c = tid & 127, h = c >> 5;
      int sBase = (tid >> 7) * 8;
      #pragma unroll
      for (int s=0;s<8;s++){
        float acc=0.f;
        #pragma unroll
        for (int ki=0;ki<16;ki++) acc += at[h][sBase+s][ki]*vf[ki][c];
        ob[sBase+s][c] = f2bf(acc);
      }
    }
    __syncthreads();
    {
      bf16x8 ao[4];
      #pragma unroll
      for (int ks=0;ks<4;ks++) ao[ks] = *(const bf16x8*)&ob[l15][ks*32+quad*8];
      #pragma unroll
      for (int nt=0; nt<2; nt++){
        const int n0 = wave*32 + nt*16;
        f32x4 acc = {0.f,0.f,0.f,0.f};
        #pragma unroll
        for (int ks=0;ks<4;ks++){
          bf16x8 bw = *(const bf16x8*)(W + (size_t)(384 + n0+l15)*DD + ks*32+quad*8);
          acc = __builtin_amdgcn_mfma_f32_16x16x32_bf16(ao[ks], bw, acc, 0,0,0);
        }
        const float bias = outb[n0+l15];
        const int col = n0 + l15;
        #pragma unroll
        for (int r=0;r<4;r++){
          int row = quad*4 + r;
          er[row][col] += acc[r] + bias;
        }
      }
    }
    __syncthreads();
    {
      int row = tid >> 4, i = tid & 15;
      const float* yr = &er[row][i*8];
      float s1=0.f, s2=0.f;
      #pragma unroll
      for (int j2=0;j2<8;j2++){ float y=yr[j2]; s1+=y; s2+=y*y; }
      #pragma unroll
      for (int msk2=1; msk2<16; msk2<<=1){
        s1 += __shfl_xor(s1, msk2, 64);
        s2 += __shfl_xor(s2, msk2, 64);
      }
      if (i==0){
        float mean = s1*(1.f/128.f);
        mu[row]=mean;
        rs[row]=rsqrtf(s2*(1.f/128.f) - mean*mean + 1e-5f);
      }
    }
    __syncthreads();
    {
      int c = tid & 127, half = tid >> 7;
      float g = lng[c], bb2 = lnb[c];
      float acc=0.f;
      #pragma unroll
      for (int s=0;s<8;s++){
        int ss = half*8+s;
        acc += (er[ss][c]-mu[ss])*rs[ss]*g + bb2;
      }
      part[half][c]=acc;
    }
    __syncthreads();
    if (tid < 128)
      meta_e[((size_t)m*BB+b)*DD + tid] = (part[0][tid]+part[1][tid]) * (1.f/16.f);
  }
}

// ---------------------------------------------------------------------------
// 6) conv as MFMA GEMM + fused max-over-t (doc already bf16: staging = copy)
#define CROWS 68
__global__ __launch_bounds__(256) void k_conv(
    const unsigned short* __restrict__ doc, const unsigned short* __restrict__ wb3,
    const unsigned short* __restrict__ wb4, const unsigned short* __restrict__ wb5,
    float* __restrict__ convp){
  __shared__ __align__(16) char smem[CROWS*CPAD*2];
  unsigned short* ds = (unsigned short*)smem;
  float* smf = (float*)smem;
  const int blk = blockIdx.x;
  const int chunk = blk & 3;
  const int j = (blk >> 2) % 3;
  const int b = blk / 12;
  const int kk = 3 + j;
  const int T = LL - kk + 1;
  const int t0 = chunk * 64;
  const int nrows = 64 + kk - 1;
  const unsigned short* wb = (j==0) ? wb3 : (j==1) ? wb4 : wb5;
  const int tid = threadIdx.x;
  for (int i = tid; i < nrows*16; i += 256){
    int row = i >> 4, q8 = i & 15;
    int gt = t0 + row;
    u16x8 v = (u16x8){0,0,0,0,0,0,0,0};
    if (gt < LL) v = *(const u16x8*)(doc + ((size_t)b*LL + gt)*DD + q8*8);
    *(u16x8*)(ds + row*CPAD + q8*8) = v;
  }
  __syncthreads();
  const int wave = tid >> 6;
  const int lane = tid & 63;
  const int l15  = lane & 15;
  const int quad = lane >> 4;
  f32x4 acc[8];
  #pragma unroll
  for (int nt=0;nt<8;nt++) acc[nt] = (f32x4){0.f,0.f,0.f,0.f};
  for (int jj=0; jj<kk; jj++){
    #pragma unroll
    for (int ks=0; ks<4; ks++){
      bf16x8 af = *(const bf16x8*)(ds + (wave*16 + l15 + jj)*CPAD + ks*32 + quad*8);
      #pragma unroll
      for (int nt=0; nt<8; nt++){
        bf16x8 bf = *(const bf16x8*)(wb + ((size_t)jj*CC + nt*16 + l15)*DD + ks*32 + quad*8);
        acc[nt] = __builtin_amdgcn_mfma_f32_16x16x32_bf16(af, bf, acc[nt], 0,0,0);
      }
    }
  }
  __syncthreads();
  #pragma unroll
  for (int nt=0; nt<8; nt++){
    float mx = -1e30f;
    #pragma unroll
    for (int r=0;r<4;r++){
      int t = t0 + wave*16 + quad*4 + r;
      mx = fmaxf(mx, (t < T) ? acc[nt][r] : -1e30f);
    }
    mx = fmaxf(mx, __shfl_xor(mx, 16, 64));
    mx = fmaxf(mx, __shfl_xor(mx, 32, 64));
    if (quad == 0) smf[wave*128 + nt*16 + l15] = mx;
  }
  __syncthreads();
  if (tid < 128){
    float m4 = fmaxf(fmaxf(smf[tid], smf[128+tid]), fmaxf(smf[256+tid], smf[384+tid]));
    convp[(((size_t)b*3 + j)*4 + chunk)*CC + tid] = m4;
  }
}

// ---------------------------------------------------------------------------
// 9) pool-reduce + fc + meta gate + classifier; block per b
__global__ __launch_bounds__(128) void k_final(
    const float* __restrict__ convp,
    const float* __restrict__ cb3, const float* __restrict__ cb4,
    const float* __restrict__ cb5,
    const float* __restrict__ fc_w, const float* __restrict__ fc_b,
    const float* __restrict__ meta_e,
    const float* __restrict__ mp_w1, const float* __restrict__ mp_b1,
    const float* __restrict__ mp_w2, const float* __restrict__ mp_b2,
    const float* __restrict__ cls_w1, const float* __restrict__ cls_b1,
    const float* __restrict__ cls_w2, const float* __restrict__ cls_b2,
    float* __restrict__ out){
  const int b = blockIdx.x;
  const int c = threadIdx.x;
  __shared__ float pooled[384];
  __shared__ float comb[256];
  __shared__ float hcls[128];
  __shared__ float tt[2][64];
  __shared__ float wsc[2];
  for (int idx=c; idx<384; idx+=128){
    int j = idx >> 7, cc2 = idx & 127;
    const float* base = convp + (((size_t)b*3 + j)*4)*CC + cc2;
    float mx = -1e30f;
    for (int ci=0;ci<4;ci++) mx = fmaxf(mx, base[ci*CC]);
    const float* cb = (j==0)?cb3:(j==1)?cb4:cb5;
    pooled[idx] = fmaxf(mx + cb[cc2], 0.f);
  }
  __syncthreads();
  {
    float acc = fc_b[c];
    const float* wr = fc_w + (size_t)c*384;
    for (int i=0;i<384;i++) acc += pooled[i]*wr[i];
    comb[c] = acc;
  }
  if (c < 64){
    for (int m=0;m<2;m++){
      const float* ev = meta_e + ((size_t)m*BB+b)*DD;
      float acc = mp_b1[c];
      const float* wr = mp_w1 + (size_t)c*DD;
      for (int i=0;i<DD;i++) acc += ev[i]*wr[i];
      tt[m][c] = tanhf(acc);
    }
  }
  __syncthreads();
  if (c == 0){
    float s0 = mp_b2[0], s1 = mp_b2[0];
    for (int j=0;j<64;j++){ s0 += tt[0][j]*mp_w2[j]; s1 += tt[1][j]*mp_w2[j]; }
    float mx = fmaxf(s0,s1);
    float e0 = __expf(s0-mx), e1 = __expf(s1-mx);
    wsc[0] = e0/(e0+e1); wsc[1] = e1/(e0+e1);
  }
  __syncthreads();
  comb[128+c] = wsc[0]*meta_e[((size_t)b)*DD + c]
              + wsc[1]*meta_e[((size_t)(BB+b))*DD + c];
  __syncthreads();
  {
    float acc = cls_b1[c];
    const float* wr = cls_w1 + (size_t)c*256;
    for (int i=0;i<256;i++) acc += comb[i]*wr[i];
    hcls[c] = fmaxf(acc, 0.f);
  }
  __syncthreads();
  if (c < 2){
    float acc = cls_b2[c];
    const float* wr = cls_w2 + (size_t)c*DD;
    for (int i=0;i<DD;i++) acc += hcls[i]*wr[i];
    out[b*2 + c] = acc;
  }
}

// ---------------------------------------------------------------------------
extern "C" void kernel_launch(void* const* d_in, const int* in_sizes, int n_in,
                              void* d_out, int out_size, void* d_ws, size_t ws_size,
                              hipStream_t stream){
  const int* news_ids = (const int*)d_in[0];
  const int* nwi      = (const int*)d_in[1];
  const int* ctx_ids  = (const int*)d_in[2];
  const int* nsn_src  = (const int*)d_in[3];
  const int* nsn_end  = (const int*)d_in[4];
  const int* nun_usr  = (const int*)d_in[5];
  const int* nun_end  = (const int*)d_in[6];
  const float* word_table   = (const float*)d_in[7];
  const float* news_table   = (const float*)d_in[8];
  const float* user_table   = (const float*)d_in[9];
  const float* source_table = (const float*)d_in[10];
  const float* wa_in_w  = (const float*)d_in[11];
  const float* wa_in_b  = (const float*)d_in[12];
  const float* wa_out_w = (const float*)d_in[13];
  const float* wa_out_b = (const float*)d_in[14];
  const float* conv_w3 = (const float*)d_in[15];
  const float* conv_b3 = (const float*)d_in[16];
  const float* conv_w4 = (const float*)d_in[17];
  const float* conv_b4 = (const float*)d_in[18];
  const float* conv_w5 = (const float*)d_in[19];
  const float* conv_b5 = (const float*)d_in[20];
  const float* fc_w = (const float*)d_in[21];
  const float* fc_b = (const float*)d_in[22];
  const float* wih0 = (const float*)d_in[23];
  const float* whh0 = (const float*)d_in[24];
  const float* bih0 = (const float*)d_in[25];
  const float* bhh0 = (const float*)d_in[26];
  const float* inw0 = (const float*)d_in[27];
  const float* inb0 = (const float*)d_in[28];
  const float* outw0 = (const float*)d_in[29];
  const float* outb0 = (const float*)d_in[30];
  const float* lng0 = (const float*)d_in[31];
  const float* lnb0 = (const float*)d_in[32];
  const float* wih1 = (const float*)d_in[33];
  const float* whh1 = (const float*)d_in[34];
  const float* bih1 = (const float*)d_in[35];
  const float* bhh1 = (const float*)d_in[36];
  const float* inw1 = (const float*)d_in[37];
  const float* inb1 = (const float*)d_in[38];
  const float* outw1 = (const float*)d_in[39];
  const float* outb1 = (const float*)d_in[40];
  const float* lng1 = (const float*)d_in[41];
  const float* lnb1 = (const float*)d_in[42];
  const float* mp_w1 = (const float*)d_in[43];
  const float* mp_b1 = (const float*)d_in[44];
  const float* mp_w2 = (const float*)d_in[45];
  const float* mp_b2 = (const float*)d_in[46];
  const float* cls_w1 = (const float*)d_in[47];
  const float* cls_b1 = (const float*)d_in[48];
  const float* cls_w2 = (const float*)d_in[49];
  const float* cls_b2 = (const float*)d_in[50];

  // workspace layout
  char* wsb = (char*)d_ws;
  unsigned short* nK = (unsigned short*)wsb;                 // NNN*DD bf16
  unsigned short* nV = nK + (size_t)NNN*DD;                  // NNN*DD bf16
  unsigned short* wb3 = nV + (size_t)NNN*DD;
  unsigned short* wb4 = wb3 + (size_t)CC*DD*3;
  unsigned short* wb5 = wb4 + (size_t)CC*DD*4;
  unsigned short* wgb = wb5 + (size_t)CC*DD*5;               // 4*384*128 bf16
  unsigned short* wab = wgb + (size_t)4*384*DD;              // 512*128 bf16
  unsigned short* wmh = wab + (size_t)512*DD;                // 2*512*128 bf16
  float* qh     = (float*)(wmh + (size_t)2*512*DD);
  unsigned short* o_at = (unsigned short*)(qh + (size_t)BB*LL*DD);   // bf16
  unsigned short* doc  = (unsigned short*)((float*)o_at + (size_t)BB*LL*DD); // bf16
  float* convp  = (float*)doc + (size_t)BB*LL*DD;
  float* enc    = convp + BB*3*4*CC;
  float* meta_e = enc + (size_t)2*BB*SS*DD;
  const size_t need_bytes = (size_t)((char*)(meta_e + 2*BB*DD) - wsb);
  if (ws_size < need_bytes) return;

  const unsigned short* wqb  = wab;                   // rows 0..127 (wq)
  const unsigned short* wkvb = wab + (size_t)128*DD;  // rows 128..383 (wk;wv)
  const unsigned short* wob  = wab + (size_t)384*DD;  // out_w

  k_prep<<<dim3(320), dim3(256), 0, stream>>>(conv_w3, conv_w4, conv_w5,
      wih0, whh0, wih1, whh1, wa_in_w, wa_out_w,
      inw0, outw0, inw1, outw1,
      wb3, wb4, wb5, wgb, wab, wmh);
  k_pq<<<dim3(PQ_PKV + 128), dim3(256), 0, stream>>>(
      news_table, wkvb, wa_in_b, nK, nV,
      word_table, nwi, wqb, qh);
  k_gru<<<dim3(128), dim3(256), 0, stream>>>(news_table, user_table, source_table,
      news_ids, nsn_src, nsn_end, nun_usr, nun_end,
      wgb, bih0, bhh0, bih1, bhh1, enc);
  k_attn<<<dim3(BB*LL), dim3(64), 0, stream>>>(qh, nK, nV, ctx_ids, o_at);
  k_fused2<<<dim3(192), dim3(256), 0, stream>>>(o_at, nwi, wob, wa_out_b, doc,
      enc, wmh, inb0, outb0, lng0, lnb0, inb1, outb1, lng1, lnb1, meta_e);
  k_conv<<<dim3(BB*3*4), dim3(256), 0, stream>>>(doc, wb3, wb4, wb5, convp);
  k_final<<<dim3(BB), dim3(128), 0, stream>>>(convp, conv_b3, conv_b4, conv_b5,
      fc_w, fc_b, meta_e, mp_w1, mp_b1, mp_w2, mp_b2,
      cls_w1, cls_b1, cls_w2, cls_b2, (float*)d_out);
}

// Round 9
// 351.602 us; speedup vs baseline: 1.0246x; 1.0028x over previous
//
#include <hip/hip_runtime.h>
#include <hip/hip_bf16.h>

// Problem dims
#define BB 32
#define LL 256
#define KC 50
#define SS 16
#define DD 128
#define NH 4
#define CC 128
#define VV 50000
#define NNN 100000
#define NUU 50000
#define NSS 5000

typedef __attribute__((ext_vector_type(8))) short bf16x8;
typedef __attribute__((ext_vector_type(8))) unsigned short u16x8;
typedef __attribute__((ext_vector_type(4))) float f32x4;

__device__ __forceinline__ float dot4(float4 a, float4 b){
  return a.x*b.x + a.y*b.y + a.z*b.z + a.w*b.w;
}

__device__ __forceinline__ unsigned short f2bf(float f){
  union { float f; unsigned int u; } v; v.f = f;
  unsigned int r = (v.u + 0x7FFFu + ((v.u >> 16) & 1u)) >> 16;
  return (unsigned short)r;
}
__device__ __forceinline__ float bf2f(unsigned short s){
  union { unsigned int u; float f; } v; v.u = ((unsigned int)s) << 16;
  return v.f;
}

// ---------------------------------------------------------------------------
// 0) unified weight prep: conv wb3/4/5, GRU wgb, word-attn wab, meta-MHA wmh
__global__ __launch_bounds__(256) void k_prep(
    const float* __restrict__ w3, const float* __restrict__ w4,
    const float* __restrict__ w5,
    const float* __restrict__ wih0, const float* __restrict__ whh0,
    const float* __restrict__ wih1, const float* __restrict__ whh1,
    const float* __restrict__ in_w, const float* __restrict__ out_w,
    const float* __restrict__ inw0, const float* __restrict__ outw0,
    const float* __restrict__ inw1, const float* __restrict__ outw1,
    unsigned short* __restrict__ wb3, unsigned short* __restrict__ wb4,
    unsigned short* __restrict__ wb5, unsigned short* __restrict__ wgb,
    unsigned short* __restrict__ wab, unsigned short* __restrict__ wmh){
  int e = blockIdx.x*256 + threadIdx.x;
  if (e < CC*DD*3){ int c=e/(DD*3), rm=e%(DD*3), d=rm/3, jj=rm%3;
    wb3[((size_t)jj*CC + c)*DD + d] = f2bf(w3[e]); }
  if (e < CC*DD*4){ int c=e/(DD*4), rm=e%(DD*4), d=rm/4, jj=rm%4;
    wb4[((size_t)jj*CC + c)*DD + d] = f2bf(w4[e]); }
  if (e < CC*DD*5){ int c=e/(DD*5), rm=e%(DD*5), d=rm/5, jj=rm%5;
    wb5[((size_t)jj*CC + c)*DD + d] = f2bf(w5[e]); }
  if (e < 384*DD){
    wgb[e]          = f2bf(wih0[e]);
    wgb[49152 + e]  = f2bf(whh0[e]);
    wgb[98304 + e]  = f2bf(wih1[e]);
    wgb[147456 + e] = f2bf(whh1[e]);
    wab[e]          = f2bf(in_w[e]);
  }
  if (e >= 384*DD && e < 512*DD) wab[e] = f2bf(out_w[e - 384*DD]);
  if (e < 512*DD){
    float s0 = (e < 384*DD) ? inw0[e] : outw0[e - 384*DD];
    float s1 = (e < 384*DD) ? inw1[e] : outw1[e - 384*DD];
    wmh[e]                 = f2bf(s0);
    wmh[(size_t)512*DD + e] = f2bf(s1);
  }
}

// ---------------------------------------------------------------------------
// FUSED PQ: projkv [0,1250) | qh [1250,1378)
// projkv branch = R5-verified body: wfr[4][4] hoisted (0.2 B-loads/MFMA),
// TST=72 full-row scratch, 128B-contiguous stores (R8 post-mortem: 64B
// segments inflated WRITE_SIZE 51->67 MB — partial-sector HBM writes).
#define PQ_PKV 1250
#define PST 136   // A-stage row stride (shorts)
#define TST 72    // transpose scratch row stride (shorts): 64 data + 8 pad
__global__ __launch_bounds__(256) void k_pq(
    const float* __restrict__ news, const unsigned short* __restrict__ wkvb,
    const float* __restrict__ in_b,
    unsigned short* __restrict__ nK, unsigned short* __restrict__ nV,
    const float* __restrict__ word_table, const int* __restrict__ widx,
    const unsigned short* __restrict__ wqb, float* __restrict__ qh_out){
  __shared__ __align__(16) unsigned short As[80*PST];   // 21760 B
  __shared__ __align__(16) unsigned short Tw[4*16*TST]; // 9216 B
  const int blk = blockIdx.x;
  const int tid = threadIdx.x;
  const int wave = tid >> 6, lane = tid & 63, l15 = lane & 15, quad = lane >> 4;

  if (blk < PQ_PKV){
    // ---------------- projkv (BM=80, R5-proven) ----------------
    const int r0 = blk * 80;
    const int cw = wave * 64;
    // B-fragments into registers (L2-hot; overlaps with A staging)
    bf16x8 wfr[4][4];
    #pragma unroll
    for (int nt=0; nt<4; nt++)
      #pragma unroll
      for (int ks=0; ks<4; ks++)
        wfr[nt][ks] = *(const bf16x8*)(wkvb + (size_t)(cw + nt*16 + l15)*DD + ks*32 + quad*8);
    float4 bv[4];
    #pragma unroll
    for (int nt=0; nt<4; nt++)
      bv[nt] = *(const float4*)(in_b + 128 + cw + nt*16 + quad*4);
    // stage A: 80 rows x 128 f32 -> bf16 LDS, fully coalesced
    for (int i = tid; i < 80*32; i += 256){
      int row = i >> 5, j = i & 31;
      float4 v = ((const float4*)(news + (size_t)(r0 + row)*DD))[j];
      unsigned short* d = As + row*PST + j*4;
      d[0]=f2bf(v.x); d[1]=f2bf(v.y); d[2]=f2bf(v.z); d[3]=f2bf(v.w);
    }
    __syncthreads();
    unsigned short* outp = (wave < 2) ? nK : nV;
    const int cwo = (wave & 1) * 64;
    unsigned short* tw = Tw + wave*16*TST;
    const int rr = lane >> 4;      // row-within-4 for store readback
    const int cc = lane & 15;      // col-chunk for store readback
    #pragma unroll
    for (int mt=0; mt<5; mt++){
      bf16x8 afr[4];
      #pragma unroll
      for (int ks=0; ks<4; ks++)
        afr[ks] = *(const bf16x8*)(As + (mt*16 + l15)*PST + ks*32 + quad*8);
      f32x4 acc[4];
      #pragma unroll
      for (int nt=0; nt<4; nt++) acc[nt] = (f32x4){0.f,0.f,0.f,0.f};
      #pragma unroll
      for (int ks=0; ks<4; ks++)
        #pragma unroll
        for (int nt=0; nt<4; nt++)
          acc[nt] = __builtin_amdgcn_mfma_f32_16x16x32_bf16(wfr[nt][ks], afr[ks], acc[nt], 0,0,0);
      #pragma unroll
      for (int nt=0; nt<4; nt++){
        unsigned short pk[4];
        pk[0] = f2bf(acc[nt][0] + bv[nt].x);
        pk[1] = f2bf(acc[nt][1] + bv[nt].y);
        pk[2] = f2bf(acc[nt][2] + bv[nt].z);
        pk[3] = f2bf(acc[nt][3] + bv[nt].w);
        *(unsigned long long*)(tw + l15*TST + nt*16 + quad*4) = *(const unsigned long long*)pk;
      }
      // wave-private transpose readback -> 128B-contiguous stores (4 rows/instr)
      const int gr0 = r0 + mt*16;
      #pragma unroll
      for (int s=0; s<4; s++){
        unsigned long long v = *(const unsigned long long*)(tw + (s*4 + rr)*TST + cc*4);
        *(unsigned long long*)(outp + (size_t)(gr0 + s*4 + rr)*DD + cwo + cc*4) = v;
      }
    }
  } else {
    // ---------------- qh: 4 waves x 16-row tiles ----------------
    const int p0 = ((blk - PQ_PKV)*4 + wave) * 16;
    const int row = widx[p0 + l15];
    const float* src = word_table + (size_t)row*DD + quad*8;
    bf16x8 afr[4];
    #pragma unroll
    for (int ks=0; ks<4; ks++){
      float4 v0 = *(const float4*)(src + ks*32);
      float4 v1 = *(const float4*)(src + ks*32 + 4);
      bf16x8 a;
      a[0]=(short)f2bf(v0.x); a[1]=(short)f2bf(v0.y); a[2]=(short)f2bf(v0.z); a[3]=(short)f2bf(v0.w);
      a[4]=(short)f2bf(v1.x); a[5]=(short)f2bf(v1.y); a[6]=(short)f2bf(v1.z); a[7]=(short)f2bf(v1.w);
      afr[ks] = a;
    }
    #pragma unroll
    for (int nt=0; nt<8; nt++){
      const int n0 = nt*16;
      bf16x8 bfr[4];
      #pragma unroll
      for (int ks=0; ks<4; ks++)
        bfr[ks] = *(const bf16x8*)(wqb + (size_t)(n0+l15)*DD + ks*32 + quad*8);
      const float bias = in_b[n0 + l15];
      f32x4 acc = {0.f,0.f,0.f,0.f};
      #pragma unroll
      for (int ks=0; ks<4; ks++)
        acc = __builtin_amdgcn_mfma_f32_16x16x32_bf16(afr[ks], bfr[ks], acc, 0,0,0);
      #pragma unroll
      for (int r=0;r<4;r++){
        int m = quad*4 + r;
        qh_out[(size_t)(p0+m)*DD + n0 + l15] = acc[r] + bias;
      }
    }
  }
}

// ---------------------------------------------------------------------------
// 7) GRU via MFMA; standalone (its 140-VGPR body must not tax other branches)
#define CPAD 136
#define GSTR 392
__global__ __launch_bounds__(256) void k_gru(
    const float* __restrict__ news_table, const float* __restrict__ user_table,
    const float* __restrict__ source_table,
    const int* __restrict__ news_ids, const int* __restrict__ nsn_src,
    const int* __restrict__ nsn_end, const int* __restrict__ nun_usr,
    const int* __restrict__ nun_end,
    const unsigned short* __restrict__ wgb,
    const float* __restrict__ bih0, const float* __restrict__ bhh0,
    const float* __restrict__ bih1, const float* __restrict__ bhh1,
    float* __restrict__ enc){
  __shared__ __align__(16) unsigned short xs[16][CPAD];
  __shared__ __align__(16) unsigned short hs[16][CPAD];
  __shared__ float hf[8][128];
  __shared__ float gi[8][GSTR];
  __shared__ float gh[8][GSTR];
  const int blk = blockIdx.x;
  const int m  = blk >> 6;
  const int b  = (blk >> 1) & 31;
  const int s0 = (blk & 1) * 8;
  const int tid = threadIdx.x;
  const int wave = tid >> 6, lane = tid & 63, l15 = lane & 15, quad = lane >> 4;
  const unsigned short* Wih = wgb + (size_t)m*2*384*DD;
  const unsigned short* Whh = Wih + 384*DD;
  const float* bih = m ? bih1 : bih0;
  const float* bhh = m ? bhh1 : bhh0;
  for (int i=tid;i<16*CPAD;i+=256){ (&xs[0][0])[i]=0; (&hs[0][0])[i]=0; }
  for (int i=tid;i<8*128;i+=256) (&hf[0][0])[i]=0.f;
  __syncthreads();
  for (int t=0;t<3;t++){
    {
      int s = tid >> 5, j = tid & 31;
      int row; const float* tab;
      if (t==0){ row = news_ids[b]; tab = news_table; }
      else if (t==1){ row = m ? nun_usr[b*SS+s0+s] : nsn_src[b*SS+s0+s];
                      tab = m ? user_table : source_table; }
      else { row = m ? nun_end[b*SS+s0+s] : nsn_end[b*SS+s0+s]; tab = news_table; }
      float4 v = ((const float4*)(tab + (size_t)row*DD))[j];
      unsigned short* dp = &xs[s][j*4];
      dp[0]=f2bf(v.x); dp[1]=f2bf(v.y); dp[2]=f2bf(v.z); dp[3]=f2bf(v.w);
    }
    __syncthreads();
    bf16x8 ax[4], ah[4];
    #pragma unroll
    for (int ks=0;ks<4;ks++){
      ax[ks] = *(const bf16x8*)&xs[l15][ks*32+quad*8];
      ah[ks] = *(const bf16x8*)&hs[l15][ks*32+quad*8];
    }
    #pragma unroll
    for (int nt=0;nt<6;nt++){
      const int n0 = wave*96 + nt*16;
      f32x4 ga = {0.f,0.f,0.f,0.f}, ha = {0.f,0.f,0.f,0.f};
      #pragma unroll
      for (int ks=0;ks<4;ks++){
        bf16x8 bi = *(const bf16x8*)(Wih + (size_t)(n0+l15)*DD + ks*32+quad*8);
        ga = __builtin_amdgcn_mfma_f32_16x16x32_bf16(ax[ks], bi, ga, 0,0,0);
        bf16x8 bh = *(const bf16x8*)(Whh + (size_t)(n0+l15)*DD + ks*32+quad*8);
        ha = __builtin_amdgcn_mfma_f32_16x16x32_bf16(ah[ks], bh, ha, 0,0,0);
      }
      if (quad < 2){
        #pragma unroll
        for (int r=0;r<4;r++){
          gi[quad*4+r][n0+l15] = ga[r];
          gh[quad*4+r][n0+l15] = ha[r];
        }
      }
    }
    __syncthreads();
    #pragma unroll
    for (int k=0;k<4;k++){
      int it = tid + k*256;
      int s = it >> 7, g = it & 127;
      float rr = 1.f/(1.f+__expf(-(gi[s][g] + gh[s][g] + bih[g] + bhh[g])));
      float zz = 1.f/(1.f+__expf(-(gi[s][128+g] + gh[s][128+g] + bih[128+g] + bhh[128+g])));
      float nn = tanhf(gi[s][256+g] + bih[256+g] + rr*(gh[s][256+g] + bhh[256+g]));
      float hnew = (1.f-zz)*nn + zz*hf[s][g];
      hf[s][g] = hnew;
      hs[s][g] = f2bf(hnew);
    }
    __syncthreads();
  }
  {
    int s = tid >> 5, j = tid & 31;
    float4 v = ((const float4*)hf[s])[j];
    ((float4*)(enc + (((size_t)m*BB + b)*SS + (s0+s))*DD))[j] = v;
  }
}

// ---------------------------------------------------------------------------
// 3) per-(b,l) attention, one wave per token; writes o as bf16.
//    Gather loops unrolled: 13 L2/L3 gathers issued in flight per phase.
__global__ __launch_bounds__(64) void k_attn(
    const float* __restrict__ qh, const unsigned short* __restrict__ nK,
    const unsigned short* __restrict__ nV, const int* __restrict__ ctx_ids,
    unsigned short* __restrict__ o_out){
  const int p = blockIdx.x;
  const int lane = threadIdx.x;
  const int r = lane >> 4;
  const int g = lane & 15;
  const int h = g >> 2;
  __shared__ int ids[52];
  __shared__ float sc[NH][52];
  if (lane < KC) ids[lane] = ctx_ids[(size_t)p*KC + lane];
  float qv[8];
  {
    const float4* qp = (const float4*)(qh + (size_t)p*DD + g*8);
    float4 q0 = qp[0], q1 = qp[1];
    qv[0]=q0.x; qv[1]=q0.y; qv[2]=q0.z; qv[3]=q0.w;
    qv[4]=q1.x; qv[5]=q1.y; qv[6]=q1.z; qv[7]=q1.w;
  }
  __syncthreads();
  #pragma unroll
  for (int kb=0; kb<13; kb++){
    int k2 = kb*4 + r;
    int row = ids[(k2 < KC) ? k2 : 0];
    u16x8 kv = *(const u16x8*)(nK + (size_t)row*DD + g*8);
    float pr = 0.f;
    #pragma unroll
    for (int j=0;j<8;j++) pr += qv[j]*bf2f(kv[j]);
    pr += __shfl_xor(pr, 1, 64);
    pr += __shfl_xor(pr, 2, 64);
    if ((g & 3) == 0 && k2 < KC) sc[h][k2] = pr;
  }
  __syncthreads();
  {
    const int hh = lane >> 4, kc = lane & 15;
    const float scale = 0.17677669529663687f;
    float mx = -1e30f;
    #pragma unroll
    for (int q4=0;q4<4;q4++){ int k2=kc+q4*16; if (k2<KC) mx = fmaxf(mx, sc[hh][k2]); }
    mx = fmaxf(mx, __shfl_xor(mx, 1, 64));
    mx = fmaxf(mx, __shfl_xor(mx, 2, 64));
    mx = fmaxf(mx, __shfl_xor(mx, 4, 64));
    mx = fmaxf(mx, __shfl_xor(mx, 8, 64));
    float sm = 0.f;
    float ev[4];
    #pragma unroll
    for (int q4=0;q4<4;q4++){
      int k2=kc+q4*16;
      ev[q4] = (k2<KC) ? __expf((sc[hh][k2]-mx)*scale) : 0.f;
      sm += ev[q4];
    }
    sm += __shfl_xor(sm, 1, 64);
    sm += __shfl_xor(sm, 2, 64);
    sm += __shfl_xor(sm, 4, 64);
    sm += __shfl_xor(sm, 8, 64);
    float inv = 1.f/sm;
    #pragma unroll
    for (int q4=0;q4<4;q4++){ int k2=kc+q4*16; if (k2<KC) sc[hh][k2] = ev[q4]*inv; }
  }
  __syncthreads();
  float acc[8];
  #pragma unroll
  for (int j=0;j<8;j++) acc[j]=0.f;
  #pragma unroll
  for (int kb=0; kb<13; kb++){
    int k2 = kb*4 + r;
    int row = ids[(k2 < KC) ? k2 : 0];
    float w = (k2 < KC) ? sc[h][k2] : 0.f;
    u16x8 vv = *(const u16x8*)(nV + (size_t)row*DD + g*8);
    #pragma unroll
    for (int j=0;j<8;j++) acc[j] += w*bf2f(vv[j]);
  }
  #pragma unroll
  for (int j=0;j<8;j++){
    acc[j] += __shfl_xor(acc[j], 16, 64);
    acc[j] += __shfl_xor(acc[j], 32, 64);
  }
  if (r == 0){
    u16x8 o;
    #pragma unroll
    for (int j=0;j<8;j++) o[j] = f2bf(acc[j]);
    *(u16x8*)(o_out + (size_t)p*DD + g*8) = o;
  }
}

// ---------------------------------------------------------------------------
// FUSED 2: wo [0,128) | metamha [128,192)
#define MPAD 136
__global__ __launch_bounds__(256) void k_fused2(
    const unsigned short* __restrict__ o_attn, const int* __restrict__ widx,
    const unsigned short* __restrict__ wob, const float* __restrict__ out_b,
    unsigned short* __restrict__ doc,
    const float* __restrict__ enc, const unsigned short* __restrict__ wmh,
    const float* __restrict__ inb0, const float* __restrict__ outb0,
    const float* __restrict__ lng0, const float* __restrict__ lnb0,
    const float* __restrict__ inb1, const float* __restrict__ outb1,
    const float* __restrict__ lng1, const float* __restrict__ lnb1,
    float* __restrict__ meta_e){
  __shared__ __align__(16) char smem[39296];
  const int blk = blockIdx.x;
  const int tid = threadIdx.x;
  const int wave = tid >> 6, lane = tid & 63, l15 = lane & 15, quad = lane >> 4;

  if (blk < 128){
    const int p0 = (blk*4 + wave) * 16;
    bf16x8 afr[4];
    #pragma unroll
    for (int ks=0; ks<4; ks++)
      afr[ks] = *(const bf16x8*)(o_attn + (size_t)(p0+l15)*DD + ks*32 + quad*8);
    int msk[4];
    #pragma unroll
    for (int r=0;r<4;r++) msk[r] = widx[p0 + quad*4 + r];
    #pragma unroll
    for (int nt=0; nt<8; nt++){
      const int n0 = nt*16;
      bf16x8 bfr[4];
      #pragma unroll
      for (int ks=0; ks<4; ks++)
        bfr[ks] = *(const bf16x8*)(wob + (size_t)(n0+l15)*DD + ks*32 + quad*8);
      const float bias = out_b[n0 + l15];
      f32x4 acc = {0.f,0.f,0.f,0.f};
      #pragma unroll
      for (int ks=0; ks<4; ks++)
        acc = __builtin_amdgcn_mfma_f32_16x16x32_bf16(afr[ks], bfr[ks], acc, 0,0,0);
      #pragma unroll
      for (int r=0;r<4;r++){
        int m = quad*4 + r;
        doc[(size_t)(p0+m)*DD + n0 + l15] = (msk[r] == 0) ? (unsigned short)0
                                                          : f2bf(acc[r] + bias);
      }
    }
  } else {
    auto ebf = (unsigned short(*)[MPAD])(smem);
    auto qb  = (unsigned short(*)[MPAD])(smem + 4352);
    auto kb  = (unsigned short(*)[MPAD])(smem + 8704);
    auto ob  = (unsigned short(*)[MPAD])(smem + 13056);
    auto vf  = (float(*)[128])(smem + 17408);
    auto er  = (float(*)[132])(smem + 25600);
    auto at  = (float(*)[16][16])(smem + 34048);
    float* mu = (float*)(smem + 38144);
    float* rs = (float*)(smem + 38208);
    auto part = (float(*)[128])(smem + 38272);
    const int mb = blk - 128;
    const int m = mb >> 5;
    const int b = mb & 31;
    const unsigned short* W = wmh + (size_t)m*512*DD;
    const float* in_b  = m ? inb1 : inb0;
    const float* outb  = m ? outb1 : outb0;
    const float* lng   = m ? lng1 : lng0;
    const float* lnb   = m ? lnb1 : lnb0;
    const float* esrc = enc + ((size_t)m*BB + b)*SS*DD;
    for (int i = tid; i < 16*32; i += 256){
      int s = i >> 5, j = i & 31;
      float4 v = ((const float4*)esrc)[i];
      ((float4*)er[s])[j] = v;
      unsigned short* dp = &ebf[s][j*4];
      dp[0]=f2bf(v.x); dp[1]=f2bf(v.y); dp[2]=f2bf(v.z); dp[3]=f2bf(v.w);
    }
    __syncthreads();
    {
      bf16x8 ax[4];
      #pragma unroll
      for (int ks=0;ks<4;ks++) ax[ks] = *(const bf16x8*)&ebf[l15][ks*32+quad*8];
      #pragma unroll
      for (int nt=0; nt<6; nt++){
        const int n0 = wave*96 + nt*16;
        f32x4 acc = {0.f,0.f,0.f,0.f};
        #pragma unroll
        for (int ks=0;ks<4;ks++){
          bf16x8 bw = *(const bf16x8*)(W + (size_t)(n0+l15)*DD + ks*32+quad*8);
          acc = __builtin_amdgcn_mfma_f32_16x16x32_bf16(ax[ks], bw, acc, 0,0,0);
        }
        const float bias = in_b[n0+l15];
        const int col = n0 + l15;
        #pragma unroll
        for (int r=0;r<4;r++){
          int row = quad*4+r;
          float val = acc[r] + bias;
          if (n0 < 128)      qb[row][col]       = f2bf(val);
          else if (n0 < 256) kb[row][col-128]   = f2bf(val);
          else               vf[row][col-256]   = val;
        }
      }
    }
    __syncthreads();
    {
      const int h = wave;
      bf16x8 aq = *(const bf16x8*)&qb[l15][h*32 + quad*8];
      bf16x8 ak = *(const bf16x8*)&kb[l15][h*32 + quad*8];
      f32x4 z = {0.f,0.f,0.f,0.f};
      f32x4 acc = __builtin_amdgcn_mfma_f32_16x16x32_bf16(aq, ak, z, 0,0,0);
      #pragma unroll
      for (int r=0;r<4;r++)
        at[h][quad*4+r][l15] = acc[r] * 0.17677669529663687f;
    }
    __syncthreads();
    if (tid < 64){
      int h = tid>>4, qi = tid&15;
      float mx=-1e30f;
      #pragma unroll
      for (int ki=0;ki<16;ki++) mx = fmaxf(mx, at[h][qi][ki]);
      float sm=0.f;
      float ee[16];
      #pragma unroll
      for (int ki=0;ki<16;ki++){ ee[ki]=__expf(at[h][qi][ki]-mx); sm+=ee[ki]; }
      float inv=1.f/sm;
      #pragma unroll
      for (int ki=0;ki<16;ki++) at[h][qi][ki]=ee[ki]*inv;
    }
    __syncthreads();
    {
      int c = tid & 127, h = c >> 5;
      int sBase = (tid >> 7) * 8;
      #pragma unroll
      for (int s=0;s<8;s++){
        float acc=0.f;
        #pragma unroll
        for (int ki=0;ki<16;ki++) acc += at[h][sBase+s][ki]*vf[ki][c];
        ob[sBase+s][c] = f2bf(acc);
      }
    }
    __syncthreads();
    {
      bf16x8 ao[4];
      #pragma unroll
      for (int ks=0;ks<4;ks++) ao[ks] = *(const bf16x8*)&ob[l15][ks*32+quad*8];
      #pragma unroll
      for (int nt=0; nt<2; nt++){
        const int n0 = wave*32 + nt*16;
        f32x4 acc = {0.f,0.f,0.f,0.f};
        #pragma unroll
        for (int ks=0;ks<4;ks++){
          bf16x8 bw = *(const bf16x8*)(W + (size_t)(384 + n0+l15)*DD + ks*32+quad*8);
          acc = __builtin_amdgcn_mfma_f32_16x16x32_bf16(ao[ks], bw, acc, 0,0,0);
        }
        const float bias = outb[n0+l15];
        const int col = n0 + l15;
        #pragma unroll
        for (int r=0;r<4;r++){
          int row = quad*4 + r;
          er[row][col] += acc[r] + bias;
        }
      }
    }
    __syncthreads();
    {
      int row = tid >> 4, i = tid & 15;
      const float* yr = &er[row][i*8];
      float s1=0.f, s2=0.f;
      #pragma unroll
      for (int j2=0;j2<8;j2++){ float y=yr[j2]; s1+=y; s2+=y*y; }
      #pragma unroll
      for (int msk2=1; msk2<16; msk2<<=1){
        s1 += __shfl_xor(s1, msk2, 64);
        s2 += __shfl_xor(s2, msk2, 64);
      }
      if (i==0){
        float mean = s1*(1.f/128.f);
        mu[row]=mean;
        rs[row]=rsqrtf(s2*(1.f/128.f) - mean*mean + 1e-5f);
      }
    }
    __syncthreads();
    {
      int c = tid & 127, half = tid >> 7;
      float g = lng[c], bb2 = lnb[c];
      float acc=0.f;
      #pragma unroll
      for (int s=0;s<8;s++){
        int ss = half*8+s;
        acc += (er[ss][c]-mu[ss])*rs[ss]*g + bb2;
      }
      part[half][c]=acc;
    }
    __syncthreads();
    if (tid < 128)
      meta_e[((size_t)m*BB+b)*DD + tid] = (part[0][tid]+part[1][tid]) * (1.f/16.f);
  }
}

// ---------------------------------------------------------------------------
// 6) conv as MFMA GEMM + fused max-over-t (doc already bf16: staging = copy)
#define CROWS 68
__global__ __launch_bounds__(256) void k_conv(
    const unsigned short* __restrict__ doc, const unsigned short* __restrict__ wb3,
    const unsigned short* __restrict__ wb4, const unsigned short* __restrict__ wb5,
    float* __restrict__ convp){
  __shared__ __align__(16) char smem[CROWS*CPAD*2];
  unsigned short* ds = (unsigned short*)smem;
  float* smf = (float*)smem;
  const int blk = blockIdx.x;
  const int chunk = blk & 3;
  const int j = (blk >> 2) % 3;
  const int b = blk / 12;
  const int kk = 3 + j;
  const int T = LL - kk + 1;
  const int t0 = chunk * 64;
  const int nrows = 64 + kk - 1;
  const unsigned short* wb = (j==0) ? wb3 : (j==1) ? wb4 : wb5;
  const int tid = threadIdx.x;
  for (int i = tid; i < nrows*16; i += 256){
    int row = i >> 4, q8 = i & 15;
    int gt = t0 + row;
    u16x8 v = (u16x8){0,0,0,0,0,0,0,0};
    if (gt < LL) v = *(const u16x8*)(doc + ((size_t)b*LL + gt)*DD + q8*8);
    *(u16x8*)(ds + row*CPAD + q8*8) = v;
  }
  __syncthreads();
  const int wave = tid >> 6;
  const int lane = tid & 63;
  const int l15  = lane & 15;
  const int quad = lane >> 4;
  f32x4 acc[8];
  #pragma unroll
  for (int nt=0;nt<8;nt++) acc[nt] = (f32x4){0.f,0.f,0.f,0.f};
  for (int jj=0; jj<kk; jj++){
    #pragma unroll
    for (int ks=0; ks<4; ks++){
      bf16x8 af = *(const bf16x8*)(ds + (wave*16 + l15 + jj)*CPAD + ks*32 + quad*8);
      #pragma unroll
      for (int nt=0; nt<8; nt++){
        bf16x8 bf = *(const bf16x8*)(wb + ((size_t)jj*CC + nt*16 + l15)*DD + ks*32 + quad*8);
        acc[nt] = __builtin_amdgcn_mfma_f32_16x16x32_bf16(af, bf, acc[nt], 0,0,0);
      }
    }
  }
  __syncthreads();
  #pragma unroll
  for (int nt=0; nt<8; nt++){
    float mx = -1e30f;
    #pragma unroll
    for (int r=0;r<4;r++){
      int t = t0 + wave*16 + quad*4 + r;
      mx = fmaxf(mx, (t < T) ? acc[nt][r] : -1e30f);
    }
    mx = fmaxf(mx, __shfl_xor(mx, 16, 64));
    mx = fmaxf(mx, __shfl_xor(mx, 32, 64));
    if (quad == 0) smf[wave*128 + nt*16 + l15] = mx;
  }
  __syncthreads();
  if (tid < 128){
    float m4 = fmaxf(fmaxf(smf[tid], smf[128+tid]), fmaxf(smf[256+tid], smf[384+tid]));
    convp[(((size_t)b*3 + j)*4 + chunk)*CC + tid] = m4;
  }
}

// ---------------------------------------------------------------------------
// 9) pool-reduce + fc + meta gate + classifier; block per b
__global__ __launch_bounds__(128) void k_final(
    const float* __restrict__ convp,
    const float* __restrict__ cb3, const float* __restrict__ cb4,
    const float* __restrict__ cb5,
    const float* __restrict__ fc_w, const float* __restrict__ fc_b,
    const float* __restrict__ meta_e,
    const float* __restrict__ mp_w1, const float* __restrict__ mp_b1,
    const float* __restrict__ mp_w2, const float* __restrict__ mp_b2,
    const float* __restrict__ cls_w1, const float* __restrict__ cls_b1,
    const float* __restrict__ cls_w2, const float* __restrict__ cls_b2,
    float* __restrict__ out){
  const int b = blockIdx.x;
  const int c = threadIdx.x;
  __shared__ float pooled[384];
  __shared__ float comb[256];
  __shared__ float hcls[128];
  __shared__ float tt[2][64];
  __shared__ float wsc[2];
  for (int idx=c; idx<384; idx+=128){
    int j = idx >> 7, cc2 = idx & 127;
    const float* base = convp + (((size_t)b*3 + j)*4)*CC + cc2;
    float mx = -1e30f;
    for (int ci=0;ci<4;ci++) mx = fmaxf(mx, base[ci*CC]);
    const float* cb = (j==0)?cb3:(j==1)?cb4:cb5;
    pooled[idx] = fmaxf(mx + cb[cc2], 0.f);
  }
  __syncthreads();
  {
    float acc = fc_b[c];
    const float* wr = fc_w + (size_t)c*384;
    for (int i=0;i<384;i++) acc += pooled[i]*wr[i];
    comb[c] = acc;
  }
  if (c < 64){
    for (int m=0;m<2;m++){
      const float* ev = meta_e + ((size_t)m*BB+b)*DD;
      float acc = mp_b1[c];
      const float* wr = mp_w1 + (size_t)c*DD;
      for (int i=0;i<DD;i++) acc += ev[i]*wr[i];
      tt[m][c] = tanhf(acc);
    }
  }
  __syncthreads();
  if (c == 0){
    float s0 = mp_b2[0], s1 = mp_b2[0];
    for (int j=0;j<64;j++){ s0 += tt[0][j]*mp_w2[j]; s1 += tt[1][j]*mp_w2[j]; }
    float mx = fmaxf(s0,s1);
    float e0 = __expf(s0-mx), e1 = __expf(s1-mx);
    wsc[0] = e0/(e0+e1); wsc[1] = e1/(e0+e1);
  }
  __syncthreads();
  comb[128+c] = wsc[0]*meta_e[((size_t)b)*DD + c]
              + wsc[1]*meta_e[((size_t)(BB+b))*DD + c];
  __syncthreads();
  {
    float acc = cls_b1[c];
    const float* wr = cls_w1 + (size_t)c*256;
    for (int i=0;i<256;i++) acc += comb[i]*wr[i];
    hcls[c] = fmaxf(acc, 0.f);
  }
  __syncthreads();
  if (c < 2){
    float acc = cls_b2[c];
    const float* wr = cls_w2 + (size_t)c*DD;
    for (int i=0;i<DD;i++) acc += hcls[i]*wr[i];
    out[b*2 + c] = acc;
  }
}

// ---------------------------------------------------------------------------
extern "C" void kernel_launch(void* const* d_in, const int* in_sizes, int n_in,
                              void* d_out, int out_size, void* d_ws, size_t ws_size,
                              hipStream_t stream){
  const int* news_ids = (const int*)d_in[0];
  const int* nwi      = (const int*)d_in[1];
  const int* ctx_ids  = (const int*)d_in[2];
  const int* nsn_src  = (const int*)d_in[3];
  const int* nsn_end  = (const int*)d_in[4];
  const int* nun_usr  = (const int*)d_in[5];
  const int* nun_end  = (const int*)d_in[6];
  const float* word_table   = (const float*)d_in[7];
  const float* news_table   = (const float*)d_in[8];
  const float* user_table   = (const float*)d_in[9];
  const float* source_table = (const float*)d_in[10];
  const float* wa_in_w  = (const float*)d_in[11];
  const float* wa_in_b  = (const float*)d_in[12];
  const float* wa_out_w = (const float*)d_in[13];
  const float* wa_out_b = (const float*)d_in[14];
  const float* conv_w3 = (const float*)d_in[15];
  const float* conv_b3 = (const float*)d_in[16];
  const float* conv_w4 = (const float*)d_in[17];
  const float* conv_b4 = (const float*)d_in[18];
  const float* conv_w5 = (const float*)d_in[19];
  const float* conv_b5 = (const float*)d_in[20];
  const float* fc_w = (const float*)d_in[21];
  const float* fc_b = (const float*)d_in[22];
  const float* wih0 = (const float*)d_in[23];
  const float* whh0 = (const float*)d_in[24];
  const float* bih0 = (const float*)d_in[25];
  const float* bhh0 = (const float*)d_in[26];
  const float* inw0 = (const float*)d_in[27];
  const float* inb0 = (const float*)d_in[28];
  const float* outw0 = (const float*)d_in[29];
  const float* outb0 = (const float*)d_in[30];
  const float* lng0 = (const float*)d_in[31];
  const float* lnb0 = (const float*)d_in[32];
  const float* wih1 = (const float*)d_in[33];
  const float* whh1 = (const float*)d_in[34];
  const float* bih1 = (const float*)d_in[35];
  const float* bhh1 = (const float*)d_in[36];
  const float* inw1 = (const float*)d_in[37];
  const float* inb1 = (const float*)d_in[38];
  const float* outw1 = (const float*)d_in[39];
  const float* outb1 = (const float*)d_in[40];
  const float* lng1 = (const float*)d_in[41];
  const float* lnb1 = (const float*)d_in[42];
  const float* mp_w1 = (const float*)d_in[43];
  const float* mp_b1 = (const float*)d_in[44];
  const float* mp_w2 = (const float*)d_in[45];
  const float* mp_b2 = (const float*)d_in[46];
  const float* cls_w1 = (const float*)d_in[47];
  const float* cls_b1 = (const float*)d_in[48];
  const float* cls_w2 = (const float*)d_in[49];
  const float* cls_b2 = (const float*)d_in[50];

  // workspace layout
  char* wsb = (char*)d_ws;
  unsigned short* nK = (unsigned short*)wsb;                 // NNN*DD bf16
  unsigned short* nV = nK + (size_t)NNN*DD;                  // NNN*DD bf16
  unsigned short* wb3 = nV + (size_t)NNN*DD;
  unsigned short* wb4 = wb3 + (size_t)CC*DD*3;
  unsigned short* wb5 = wb4 + (size_t)CC*DD*4;
  unsigned short* wgb = wb5 + (size_t)CC*DD*5;               // 4*384*128 bf16
  unsigned short* wab = wgb + (size_t)4*384*DD;              // 512*128 bf16
  unsigned short* wmh = wab + (size_t)512*DD;                // 2*512*128 bf16
  float* qh     = (float*)(wmh + (size_t)2*512*DD);
  unsigned short* o_at = (unsigned short*)(qh + (size_t)BB*LL*DD);   // bf16
  unsigned short* doc  = (unsigned short*)((float*)o_at + (size_t)BB*LL*DD); // bf16
  float* convp  = (float*)doc + (size_t)BB*LL*DD;
  float* enc    = convp + BB*3*4*CC;
  float* meta_e = enc + (size_t)2*BB*SS*DD;
  const size_t need_bytes = (size_t)((char*)(meta_e + 2*BB*DD) - wsb);
  if (ws_size < need_bytes) return;

  const unsigned short* wqb  = wab;                   // rows 0..127 (wq)
  const unsigned short* wkvb = wab + (size_t)128*DD;  // rows 128..383 (wk;wv)
  const unsigned short* wob  = wab + (size_t)384*DD;  // out_w

  k_prep<<<dim3(320), dim3(256), 0, stream>>>(conv_w3, conv_w4, conv_w5,
      wih0, whh0, wih1, whh1, wa_in_w, wa_out_w,
      inw0, outw0, inw1, outw1,
      wb3, wb4, wb5, wgb, wab, wmh);
  k_pq<<<dim3(PQ_PKV + 128), dim3(256), 0, stream>>>(
      news_table, wkvb, wa_in_b, nK, nV,
      word_table, nwi, wqb, qh);
  k_gru<<<dim3(128), dim3(256), 0, stream>>>(news_table, user_table, source_table,
      news_ids, nsn_src, nsn_end, nun_usr, nun_end,
      wgb, bih0, bhh0, bih1, bhh1, enc);
  k_attn<<<dim3(BB*LL), dim3(64), 0, stream>>>(qh, nK, nV, ctx_ids, o_at);
  k_fused2<<<dim3(192), dim3(256), 0, stream>>>(o_at, nwi, wob, wa_out_b, doc,
      enc, wmh, inb0, outb0, lng0, lnb0, inb1, outb1, lng1, lnb1, meta_e);
  k_conv<<<dim3(BB*3*4), dim3(256), 0, stream>>>(doc, wb3, wb4, wb5, convp);
  k_final<<<dim3(BB), dim3(128), 0, stream>>>(convp, conv_b3, conv_b4, conv_b5,
      fc_w, fc_b, meta_e, mp_w1, mp_b1, mp_w2, mp_b2,
      cls_w1, cls_b1, cls_w2, cls_b2, (float*)d_out);
}

// Round 10
// 349.711 us; speedup vs baseline: 1.0301x; 1.0054x over previous
//
#include <hip/hip_runtime.h>
#include <hip/hip_bf16.h>

// Problem dims
#define BB 32
#define LL 256
#define KC 50
#define SS 16
#define DD 128
#define NH 4
#define CC 128
#define VV 50000
#define NNN 100000
#define NUU 50000
#define NSS 5000

typedef __attribute__((ext_vector_type(8))) short bf16x8;
typedef __attribute__((ext_vector_type(8))) unsigned short u16x8;
typedef __attribute__((ext_vector_type(4))) float f32x4;

__device__ __forceinline__ float dot4(float4 a, float4 b){
  return a.x*b.x + a.y*b.y + a.z*b.z + a.w*b.w;
}

__device__ __forceinline__ unsigned short f2bf(float f){
  union { float f; unsigned int u; } v; v.f = f;
  unsigned int r = (v.u + 0x7FFFu + ((v.u >> 16) & 1u)) >> 16;
  return (unsigned short)r;
}
__device__ __forceinline__ float bf2f(unsigned short s){
  union { unsigned int u; float f; } v; v.u = ((unsigned int)s) << 16;
  return v.f;
}

// ---------------------------------------------------------------------------
// 0) unified weight prep: conv wb3/4/5, GRU wgb, word-attn wab, meta-MHA wmh
__global__ __launch_bounds__(256) void k_prep(
    const float* __restrict__ w3, const float* __restrict__ w4,
    const float* __restrict__ w5,
    const float* __restrict__ wih0, const float* __restrict__ whh0,
    const float* __restrict__ wih1, const float* __restrict__ whh1,
    const float* __restrict__ in_w, const float* __restrict__ out_w,
    const float* __restrict__ inw0, const float* __restrict__ outw0,
    const float* __restrict__ inw1, const float* __restrict__ outw1,
    unsigned short* __restrict__ wb3, unsigned short* __restrict__ wb4,
    unsigned short* __restrict__ wb5, unsigned short* __restrict__ wgb,
    unsigned short* __restrict__ wab, unsigned short* __restrict__ wmh){
  int e = blockIdx.x*256 + threadIdx.x;
  if (e < CC*DD*3){ int c=e/(DD*3), rm=e%(DD*3), d=rm/3, jj=rm%3;
    wb3[((size_t)jj*CC + c)*DD + d] = f2bf(w3[e]); }
  if (e < CC*DD*4){ int c=e/(DD*4), rm=e%(DD*4), d=rm/4, jj=rm%4;
    wb4[((size_t)jj*CC + c)*DD + d] = f2bf(w4[e]); }
  if (e < CC*DD*5){ int c=e/(DD*5), rm=e%(DD*5), d=rm/5, jj=rm%5;
    wb5[((size_t)jj*CC + c)*DD + d] = f2bf(w5[e]); }
  if (e < 384*DD){
    wgb[e]          = f2bf(wih0[e]);
    wgb[49152 + e]  = f2bf(whh0[e]);
    wgb[98304 + e]  = f2bf(wih1[e]);
    wgb[147456 + e] = f2bf(whh1[e]);
    wab[e]          = f2bf(in_w[e]);
  }
  if (e >= 384*DD && e < 512*DD) wab[e] = f2bf(out_w[e - 384*DD]);
  if (e < 512*DD){
    float s0 = (e < 384*DD) ? inw0[e] : outw0[e - 384*DD];
    float s1 = (e < 384*DD) ? inw1[e] : outw1[e - 384*DD];
    wmh[e]                 = f2bf(s0);
    wmh[(size_t)512*DD + e] = f2bf(s1);
  }
}

// ---------------------------------------------------------------------------
// FUSED PQ: projkv [0,1250) | qh [1250,1378)
// projkv branch = R5-verified body: wfr[4][4] hoisted (0.2 B-loads/MFMA),
// TST=72 full-row scratch, 128B-contiguous stores.
#define PQ_PKV 1250
#define PST 136   // A-stage row stride (shorts)
#define TST 72    // transpose scratch row stride (shorts): 64 data + 8 pad
__global__ __launch_bounds__(256) void k_pq(
    const float* __restrict__ news, const unsigned short* __restrict__ wkvb,
    const float* __restrict__ in_b,
    unsigned short* __restrict__ nK, unsigned short* __restrict__ nV,
    const float* __restrict__ word_table, const int* __restrict__ widx,
    const unsigned short* __restrict__ wqb, float* __restrict__ qh_out){
  __shared__ __align__(16) unsigned short As[80*PST];   // 21760 B
  __shared__ __align__(16) unsigned short Tw[4*16*TST]; // 9216 B
  const int blk = blockIdx.x;
  const int tid = threadIdx.x;
  const int wave = tid >> 6, lane = tid & 63, l15 = lane & 15, quad = lane >> 4;

  if (blk < PQ_PKV){
    // ---------------- projkv (BM=80, R5-proven) ----------------
    const int r0 = blk * 80;
    const int cw = wave * 64;
    bf16x8 wfr[4][4];
    #pragma unroll
    for (int nt=0; nt<4; nt++)
      #pragma unroll
      for (int ks=0; ks<4; ks++)
        wfr[nt][ks] = *(const bf16x8*)(wkvb + (size_t)(cw + nt*16 + l15)*DD + ks*32 + quad*8);
    float4 bv[4];
    #pragma unroll
    for (int nt=0; nt<4; nt++)
      bv[nt] = *(const float4*)(in_b + 128 + cw + nt*16 + quad*4);
    for (int i = tid; i < 80*32; i += 256){
      int row = i >> 5, j = i & 31;
      float4 v = ((const float4*)(news + (size_t)(r0 + row)*DD))[j];
      unsigned short* d = As + row*PST + j*4;
      d[0]=f2bf(v.x); d[1]=f2bf(v.y); d[2]=f2bf(v.z); d[3]=f2bf(v.w);
    }
    __syncthreads();
    unsigned short* outp = (wave < 2) ? nK : nV;
    const int cwo = (wave & 1) * 64;
    unsigned short* tw = Tw + wave*16*TST;
    const int rr = lane >> 4;
    const int cc = lane & 15;
    #pragma unroll
    for (int mt=0; mt<5; mt++){
      bf16x8 afr[4];
      #pragma unroll
      for (int ks=0; ks<4; ks++)
        afr[ks] = *(const bf16x8*)(As + (mt*16 + l15)*PST + ks*32 + quad*8);
      f32x4 acc[4];
      #pragma unroll
      for (int nt=0; nt<4; nt++) acc[nt] = (f32x4){0.f,0.f,0.f,0.f};
      #pragma unroll
      for (int ks=0; ks<4; ks++)
        #pragma unroll
        for (int nt=0; nt<4; nt++)
          acc[nt] = __builtin_amdgcn_mfma_f32_16x16x32_bf16(wfr[nt][ks], afr[ks], acc[nt], 0,0,0);
      #pragma unroll
      for (int nt=0; nt<4; nt++){
        unsigned short pk[4];
        pk[0] = f2bf(acc[nt][0] + bv[nt].x);
        pk[1] = f2bf(acc[nt][1] + bv[nt].y);
        pk[2] = f2bf(acc[nt][2] + bv[nt].z);
        pk[3] = f2bf(acc[nt][3] + bv[nt].w);
        *(unsigned long long*)(tw + l15*TST + nt*16 + quad*4) = *(const unsigned long long*)pk;
      }
      const int gr0 = r0 + mt*16;
      #pragma unroll
      for (int s=0; s<4; s++){
        unsigned long long v = *(const unsigned long long*)(tw + (s*4 + rr)*TST + cc*4);
        *(unsigned long long*)(outp + (size_t)(gr0 + s*4 + rr)*DD + cwo + cc*4) = v;
      }
    }
  } else {
    // ---------------- qh: 4 waves x 16-row tiles ----------------
    const int p0 = ((blk - PQ_PKV)*4 + wave) * 16;
    const int row = widx[p0 + l15];
    const float* src = word_table + (size_t)row*DD + quad*8;
    bf16x8 afr[4];
    #pragma unroll
    for (int ks=0; ks<4; ks++){
      float4 v0 = *(const float4*)(src + ks*32);
      float4 v1 = *(const float4*)(src + ks*32 + 4);
      bf16x8 a;
      a[0]=(short)f2bf(v0.x); a[1]=(short)f2bf(v0.y); a[2]=(short)f2bf(v0.z); a[3]=(short)f2bf(v0.w);
      a[4]=(short)f2bf(v1.x); a[5]=(short)f2bf(v1.y); a[6]=(short)f2bf(v1.z); a[7]=(short)f2bf(v1.w);
      afr[ks] = a;
    }
    #pragma unroll
    for (int nt=0; nt<8; nt++){
      const int n0 = nt*16;
      bf16x8 bfr[4];
      #pragma unroll
      for (int ks=0; ks<4; ks++)
        bfr[ks] = *(const bf16x8*)(wqb + (size_t)(n0+l15)*DD + ks*32 + quad*8);
      const float bias = in_b[n0 + l15];
      f32x4 acc = {0.f,0.f,0.f,0.f};
      #pragma unroll
      for (int ks=0; ks<4; ks++)
        acc = __builtin_amdgcn_mfma_f32_16x16x32_bf16(afr[ks], bfr[ks], acc, 0,0,0);
      #pragma unroll
      for (int r=0;r<4;r++){
        int m = quad*4 + r;
        qh_out[(size_t)(p0+m)*DD + n0 + l15] = acc[r] + bias;
      }
    }
  }
}

// ---------------------------------------------------------------------------
// 7) GRU via MFMA; standalone (its 140-VGPR body must not tax other branches)
#define CPAD 136
#define GSTR 392
__global__ __launch_bounds__(256) void k_gru(
    const float* __restrict__ news_table, const float* __restrict__ user_table,
    const float* __restrict__ source_table,
    const int* __restrict__ news_ids, const int* __restrict__ nsn_src,
    const int* __restrict__ nsn_end, const int* __restrict__ nun_usr,
    const int* __restrict__ nun_end,
    const unsigned short* __restrict__ wgb,
    const float* __restrict__ bih0, const float* __restrict__ bhh0,
    const float* __restrict__ bih1, const float* __restrict__ bhh1,
    float* __restrict__ enc){
  __shared__ __align__(16) unsigned short xs[16][CPAD];
  __shared__ __align__(16) unsigned short hs[16][CPAD];
  __shared__ float hf[8][128];
  __shared__ float gi[8][GSTR];
  __shared__ float gh[8][GSTR];
  const int blk = blockIdx.x;
  const int m  = blk >> 6;
  const int b  = (blk >> 1) & 31;
  const int s0 = (blk & 1) * 8;
  const int tid = threadIdx.x;
  const int wave = tid >> 6, lane = tid & 63, l15 = lane & 15, quad = lane >> 4;
  const unsigned short* Wih = wgb + (size_t)m*2*384*DD;
  const unsigned short* Whh = Wih + 384*DD;
  const float* bih = m ? bih1 : bih0;
  const float* bhh = m ? bhh1 : bhh0;
  for (int i=tid;i<16*CPAD;i+=256){ (&xs[0][0])[i]=0; (&hs[0][0])[i]=0; }
  for (int i=tid;i<8*128;i+=256) (&hf[0][0])[i]=0.f;
  __syncthreads();
  for (int t=0;t<3;t++){
    {
      int s = tid >> 5, j = tid & 31;
      int row; const float* tab;
      if (t==0){ row = news_ids[b]; tab = news_table; }
      else if (t==1){ row = m ? nun_usr[b*SS+s0+s] : nsn_src[b*SS+s0+s];
                      tab = m ? user_table : source_table; }
      else { row = m ? nun_end[b*SS+s0+s] : nsn_end[b*SS+s0+s]; tab = news_table; }
      float4 v = ((const float4*)(tab + (size_t)row*DD))[j];
      unsigned short* dp = &xs[s][j*4];
      dp[0]=f2bf(v.x); dp[1]=f2bf(v.y); dp[2]=f2bf(v.z); dp[3]=f2bf(v.w);
    }
    __syncthreads();
    bf16x8 ax[4], ah[4];
    #pragma unroll
    for (int ks=0;ks<4;ks++){
      ax[ks] = *(const bf16x8*)&xs[l15][ks*32+quad*8];
      ah[ks] = *(const bf16x8*)&hs[l15][ks*32+quad*8];
    }
    #pragma unroll
    for (int nt=0;nt<6;nt++){
      const int n0 = wave*96 + nt*16;
      f32x4 ga = {0.f,0.f,0.f,0.f}, ha = {0.f,0.f,0.f,0.f};
      #pragma unroll
      for (int ks=0;ks<4;ks++){
        bf16x8 bi = *(const bf16x8*)(Wih + (size_t)(n0+l15)*DD + ks*32+quad*8);
        ga = __builtin_amdgcn_mfma_f32_16x16x32_bf16(ax[ks], bi, ga, 0,0,0);
        bf16x8 bh = *(const bf16x8*)(Whh + (size_t)(n0+l15)*DD + ks*32+quad*8);
        ha = __builtin_amdgcn_mfma_f32_16x16x32_bf16(ah[ks], bh, ha, 0,0,0);
      }
      if (quad < 2){
        #pragma unroll
        for (int r=0;r<4;r++){
          gi[quad*4+r][n0+l15] = ga[r];
          gh[quad*4+r][n0+l15] = ha[r];
        }
      }
    }
    __syncthreads();
    #pragma unroll
    for (int k=0;k<4;k++){
      int it = tid + k*256;
      int s = it >> 7, g = it & 127;
      float rr = 1.f/(1.f+__expf(-(gi[s][g] + gh[s][g] + bih[g] + bhh[g])));
      float zz = 1.f/(1.f+__expf(-(gi[s][128+g] + gh[s][128+g] + bih[128+g] + bhh[128+g])));
      float nn = tanhf(gi[s][256+g] + bih[256+g] + rr*(gh[s][256+g] + bhh[256+g]));
      float hnew = (1.f-zz)*nn + zz*hf[s][g];
      hf[s][g] = hnew;
      hs[s][g] = f2bf(hnew);
    }
    __syncthreads();
  }
  {
    int s = tid >> 5, j = tid & 31;
    float4 v = ((const float4*)hf[s])[j];
    ((float4*)(enc + (((size_t)m*BB + b)*SS + (s0+s))*DD))[j] = v;
  }
}

// ---------------------------------------------------------------------------
// 3) word-attention; 4 tokens per 256-thread block (wave = token).
//    R9 lesson: 64-thr blocks cap at ~16 waves/CU (workgroup slots);
//    256-thr blocks reach 32 waves/CU for this latency-bound gather.
__global__ __launch_bounds__(256) void k_attn(
    const float* __restrict__ qh, const unsigned short* __restrict__ nK,
    const unsigned short* __restrict__ nV, const int* __restrict__ ctx_ids,
    unsigned short* __restrict__ o_out){
  const int tid = threadIdx.x;
  const int wave = tid >> 6;
  const int lane = tid & 63;
  const int p = blockIdx.x*4 + wave;
  const int r = lane >> 4;
  const int g = lane & 15;
  const int h = g >> 2;
  __shared__ int ids[4][52];
  __shared__ float sc[4][NH][52];
  if (lane < KC) ids[wave][lane] = ctx_ids[(size_t)p*KC + lane];
  float qv[8];
  {
    const float4* qp = (const float4*)(qh + (size_t)p*DD + g*8);
    float4 q0 = qp[0], q1 = qp[1];
    qv[0]=q0.x; qv[1]=q0.y; qv[2]=q0.z; qv[3]=q0.w;
    qv[4]=q1.x; qv[5]=q1.y; qv[6]=q1.z; qv[7]=q1.w;
  }
  __syncthreads();
  #pragma unroll
  for (int kb=0; kb<13; kb++){
    int k2 = kb*4 + r;
    int row = ids[wave][(k2 < KC) ? k2 : 0];
    u16x8 kv = *(const u16x8*)(nK + (size_t)row*DD + g*8);
    float pr = 0.f;
    #pragma unroll
    for (int j=0;j<8;j++) pr += qv[j]*bf2f(kv[j]);
    pr += __shfl_xor(pr, 1, 64);
    pr += __shfl_xor(pr, 2, 64);
    if ((g & 3) == 0 && k2 < KC) sc[wave][h][k2] = pr;
  }
  __syncthreads();
  {
    const int hh = lane >> 4, kc = lane & 15;
    const float scale = 0.17677669529663687f;
    float mx = -1e30f;
    #pragma unroll
    for (int q4=0;q4<4;q4++){ int k2=kc+q4*16; if (k2<KC) mx = fmaxf(mx, sc[wave][hh][k2]); }
    mx = fmaxf(mx, __shfl_xor(mx, 1, 64));
    mx = fmaxf(mx, __shfl_xor(mx, 2, 64));
    mx = fmaxf(mx, __shfl_xor(mx, 4, 64));
    mx = fmaxf(mx, __shfl_xor(mx, 8, 64));
    float sm = 0.f;
    float ev[4];
    #pragma unroll
    for (int q4=0;q4<4;q4++){
      int k2=kc+q4*16;
      ev[q4] = (k2<KC) ? __expf((sc[wave][hh][k2]-mx)*scale) : 0.f;
      sm += ev[q4];
    }
    sm += __shfl_xor(sm, 1, 64);
    sm += __shfl_xor(sm, 2, 64);
    sm += __shfl_xor(sm, 4, 64);
    sm += __shfl_xor(sm, 8, 64);
    float inv = 1.f/sm;
    #pragma unroll
    for (int q4=0;q4<4;q4++){ int k2=kc+q4*16; if (k2<KC) sc[wave][hh][k2] = ev[q4]*inv; }
  }
  __syncthreads();
  float acc[8];
  #pragma unroll
  for (int j=0;j<8;j++) acc[j]=0.f;
  #pragma unroll
  for (int kb=0; kb<13; kb++){
    int k2 = kb*4 + r;
    int row = ids[wave][(k2 < KC) ? k2 : 0];
    float w = (k2 < KC) ? sc[wave][h][k2] : 0.f;
    u16x8 vv = *(const u16x8*)(nV + (size_t)row*DD + g*8);
    #pragma unroll
    for (int j=0;j<8;j++) acc[j] += w*bf2f(vv[j]);
  }
  #pragma unroll
  for (int j=0;j<8;j++){
    acc[j] += __shfl_xor(acc[j], 16, 64);
    acc[j] += __shfl_xor(acc[j], 32, 64);
  }
  if (r == 0){
    u16x8 o;
    #pragma unroll
    for (int j=0;j<8;j++) o[j] = f2bf(acc[j]);
    *(u16x8*)(o_out + (size_t)p*DD + g*8) = o;
  }
}

// ---------------------------------------------------------------------------
// FUSED 2: wo [0,128) | metamha [128,192)
#define MPAD 136
__global__ __launch_bounds__(256) void k_fused2(
    const unsigned short* __restrict__ o_attn, const int* __restrict__ widx,
    const unsigned short* __restrict__ wob, const float* __restrict__ out_b,
    unsigned short* __restrict__ doc,
    const float* __restrict__ enc, const unsigned short* __restrict__ wmh,
    const float* __restrict__ inb0, const float* __restrict__ outb0,
    const float* __restrict__ lng0, const float* __restrict__ lnb0,
    const float* __restrict__ inb1, const float* __restrict__ outb1,
    const float* __restrict__ lng1, const float* __restrict__ lnb1,
    float* __restrict__ meta_e){
  __shared__ __align__(16) char smem[39296];
  const int blk = blockIdx.x;
  const int tid = threadIdx.x;
  const int wave = tid >> 6, lane = tid & 63, l15 = lane & 15, quad = lane >> 4;

  if (blk < 128){
    const int p0 = (blk*4 + wave) * 16;
    bf16x8 afr[4];
    #pragma unroll
    for (int ks=0; ks<4; ks++)
      afr[ks] = *(const bf16x8*)(o_attn + (size_t)(p0+l15)*DD + ks*32 + quad*8);
    int msk[4];
    #pragma unroll
    for (int r=0;r<4;r++) msk[r] = widx[p0 + quad*4 + r];
    #pragma unroll
    for (int nt=0; nt<8; nt++){
      const int n0 = nt*16;
      bf16x8 bfr[4];
      #pragma unroll
      for (int ks=0; ks<4; ks++)
        bfr[ks] = *(const bf16x8*)(wob + (size_t)(n0+l15)*DD + ks*32 + quad*8);
      const float bias = out_b[n0 + l15];
      f32x4 acc = {0.f,0.f,0.f,0.f};
      #pragma unroll
      for (int ks=0; ks<4; ks++)
        acc = __builtin_amdgcn_mfma_f32_16x16x32_bf16(afr[ks], bfr[ks], acc, 0,0,0);
      #pragma unroll
      for (int r=0;r<4;r++){
        int m = quad*4 + r;
        doc[(size_t)(p0+m)*DD + n0 + l15] = (msk[r] == 0) ? (unsigned short)0
                                                          : f2bf(acc[r] + bias);
      }
    }
  } else {
    auto ebf = (unsigned short(*)[MPAD])(smem);
    auto qb  = (unsigned short(*)[MPAD])(smem + 4352);
    auto kb  = (unsigned short(*)[MPAD])(smem + 8704);
    auto ob  = (unsigned short(*)[MPAD])(smem + 13056);
    auto vf  = (float(*)[128])(smem + 17408);
    auto er  = (float(*)[132])(smem + 25600);
    auto at  = (float(*)[16][16])(smem + 34048);
    float* mu = (float*)(smem + 38144);
    float* rs = (float*)(smem + 38208);
    auto part = (float(*)[128])(smem + 38272);
    const int mb = blk - 128;
    const int m = mb >> 5;
    const int b = mb & 31;
    const unsigned short* W = wmh + (size_t)m*512*DD;
    const float* in_b  = m ? inb1 : inb0;
    const float* outb  = m ? outb1 : outb0;
    const float* lng   = m ? lng1 : lng0;
    const float* lnb   = m ? lnb1 : lnb0;
    const float* esrc = enc + ((size_t)m*BB + b)*SS*DD;
    for (int i = tid; i < 16*32; i += 256){
      int s = i >> 5, j = i & 31;
      float4 v = ((const float4*)esrc)[i];
      ((float4*)er[s])[j] = v;
      unsigned short* dp = &ebf[s][j*4];
      dp[0]=f2bf(v.x); dp[1]=f2bf(v.y); dp[2]=f2bf(v.z); dp[3]=f2bf(v.w);
    }
    __syncthreads();
    {
      bf16x8 ax[4];
      #pragma unroll
      for (int ks=0;ks<4;ks++) ax[ks] = *(const bf16x8*)&ebf[l15][ks*32+quad*8];
      #pragma unroll
      for (int nt=0; nt<6; nt++){
        const int n0 = wave*96 + nt*16;
        f32x4 acc = {0.f,0.f,0.f,0.f};
        #pragma unroll
        for (int ks=0;ks<4;ks++){
          bf16x8 bw = *(const bf16x8*)(W + (size_t)(n0+l15)*DD + ks*32+quad*8);
          acc = __builtin_amdgcn_mfma_f32_16x16x32_bf16(ax[ks], bw, acc, 0,0,0);
        }
        const float bias = in_b[n0+l15];
        const int col = n0 + l15;
        #pragma unroll
        for (int r=0;r<4;r++){
          int row = quad*4+r;
          float val = acc[r] + bias;
          if (n0 < 128)      qb[row][col]       = f2bf(val);
          else if (n0 < 256) kb[row][col-128]   = f2bf(val);
          else               vf[row][col-256]   = val;
        }
      }
    }
    __syncthreads();
    {
      const int h = wave;
      bf16x8 aq = *(const bf16x8*)&qb[l15][h*32 + quad*8];
      bf16x8 ak = *(const bf16x8*)&kb[l15][h*32 + quad*8];
      f32x4 z = {0.f,0.f,0.f,0.f};
      f32x4 acc = __builtin_amdgcn_mfma_f32_16x16x32_bf16(aq, ak, z, 0,0,0);
      #pragma unroll
      for (int r=0;r<4;r++)
        at[h][quad*4+r][l15] = acc[r] * 0.17677669529663687f;
    }
    __syncthreads();
    if (tid < 64){
      int h = tid>>4, qi = tid&15;
      float mx=-1e30f;
      #pragma unroll
      for (int ki=0;ki<16;ki++) mx = fmaxf(mx, at[h][qi][ki]);
      float sm=0.f;
      float ee[16];
      #pragma unroll
      for (int ki=0;ki<16;ki++){ ee[ki]=__expf(at[h][qi][ki]-mx); sm+=ee[ki]; }
      float inv=1.f/sm;
      #pragma unroll
      for (int ki=0;ki<16;ki++) at[h][qi][ki]=ee[ki]*inv;
    }
    __syncthreads();
    {
      int c = tid & 127, h = c >> 5;
      int sBase = (tid >> 7) * 8;
      #pragma unroll
      for (int s=0;s<8;s++){
        float acc=0.f;
        #pragma unroll
        for (int ki=0;ki<16;ki++) acc += at[h][sBase+s][ki]*vf[ki][c];
        ob[sBase+s][c] = f2bf(acc);
      }
    }
    __syncthreads();
    {
      bf16x8 ao[4];
      #pragma unroll
      for (int ks=0;ks<4;ks++) ao[ks] = *(const bf16x8*)&ob[l15][ks*32+quad*8];
      #pragma unroll
      for (int nt=0; nt<2; nt++){
        const int n0 = wave*32 + nt*16;
        f32x4 acc = {0.f,0.f,0.f,0.f};
        #pragma unroll
        for (int ks=0;ks<4;ks++){
          bf16x8 bw = *(const bf16x8*)(W + (size_t)(384 + n0+l15)*DD + ks*32+quad*8);
          acc = __builtin_amdgcn_mfma_f32_16x16x32_bf16(ao[ks], bw, acc, 0,0,0);
        }
        const float bias = outb[n0+l15];
        const int col = n0 + l15;
        #pragma unroll
        for (int r=0;r<4;r++){
          int row = quad*4 + r;
          er[row][col] += acc[r] + bias;
        }
      }
    }
    __syncthreads();
    {
      int row = tid >> 4, i = tid & 15;
      const float* yr = &er[row][i*8];
      float s1=0.f, s2=0.f;
      #pragma unroll
      for (int j2=0;j2<8;j2++){ float y=yr[j2]; s1+=y; s2+=y*y; }
      #pragma unroll
      for (int msk2=1; msk2<16; msk2<<=1){
        s1 += __shfl_xor(s1, msk2, 64);
        s2 += __shfl_xor(s2, msk2, 64);
      }
      if (i==0){
        float mean = s1*(1.f/128.f);
        mu[row]=mean;
        rs[row]=rsqrtf(s2*(1.f/128.f) - mean*mean + 1e-5f);
      }
    }
    __syncthreads();
    {
      int c = tid & 127, half = tid >> 7;
      float g = lng[c], bb2 = lnb[c];
      float acc=0.f;
      #pragma unroll
      for (int s=0;s<8;s++){
        int ss = half*8+s;
        acc += (er[ss][c]-mu[ss])*rs[ss]*g + bb2;
      }
      part[half][c]=acc;
    }
    __syncthreads();
    if (tid < 128)
      meta_e[((size_t)m*BB+b)*DD + tid] = (part[0][tid]+part[1][tid]) * (1.f/16.f);
  }
}

// ---------------------------------------------------------------------------
// 6) conv as MFMA GEMM + fused max-over-t (doc already bf16: staging = copy)
#define CROWS 68
__global__ __launch_bounds__(256) void k_conv(
    const unsigned short* __restrict__ doc, const unsigned short* __restrict__ wb3,
    const unsigned short* __restrict__ wb4, const unsigned short* __restrict__ wb5,
    float* __restrict__ convp){
  __shared__ __align__(16) char smem[CROWS*CPAD*2];
  unsigned short* ds = (unsigned short*)smem;
  float* smf = (float*)smem;
  const int blk = blockIdx.x;
  const int chunk = blk & 3;
  const int j = (blk >> 2) % 3;
  const int b = blk / 12;
  const int kk = 3 + j;
  const int T = LL - kk + 1;
  const int t0 = chunk * 64;
  const int nrows = 64 + kk - 1;
  const unsigned short* wb = (j==0) ? wb3 : (j==1) ? wb4 : wb5;
  const int tid = threadIdx.x;
  for (int i = tid; i < nrows*16; i += 256){
    int row = i >> 4, q8 = i & 15;
    int gt = t0 + row;
    u16x8 v = (u16x8){0,0,0,0,0,0,0,0};
    if (gt < LL) v = *(const u16x8*)(doc + ((size_t)b*LL + gt)*DD + q8*8);
    *(u16x8*)(ds + row*CPAD + q8*8) = v;
  }
  __syncthreads();
  const int wave = tid >> 6;
  const int lane = tid & 63;
  const int l15  = lane & 15;
  const int quad = lane >> 4;
  f32x4 acc[8];
  #pragma unroll
  for (int nt=0;nt<8;nt++) acc[nt] = (f32x4){0.f,0.f,0.f,0.f};
  for (int jj=0; jj<kk; jj++){
    #pragma unroll
    for (int ks=0; ks<4; ks++){
      bf16x8 af = *(const bf16x8*)(ds + (wave*16 + l15 + jj)*CPAD + ks*32 + quad*8);
      #pragma unroll
      for (int nt=0; nt<8; nt++){
        bf16x8 bf = *(const bf16x8*)(wb + ((size_t)jj*CC + nt*16 + l15)*DD + ks*32 + quad*8);
        acc[nt] = __builtin_amdgcn_mfma_f32_16x16x32_bf16(af, bf, acc[nt], 0,0,0);
      }
    }
  }
  __syncthreads();
  #pragma unroll
  for (int nt=0; nt<8; nt++){
    float mx = -1e30f;
    #pragma unroll
    for (int r=0;r<4;r++){
      int t = t0 + wave*16 + quad*4 + r;
      mx = fmaxf(mx, (t < T) ? acc[nt][r] : -1e30f);
    }
    mx = fmaxf(mx, __shfl_xor(mx, 16, 64));
    mx = fmaxf(mx, __shfl_xor(mx, 32, 64));
    if (quad == 0) smf[wave*128 + nt*16 + l15] = mx;
  }
  __syncthreads();
  if (tid < 128){
    float m4 = fmaxf(fmaxf(smf[tid], smf[128+tid]), fmaxf(smf[256+tid], smf[384+tid]));
    convp[(((size_t)b*3 + j)*4 + chunk)*CC + tid] = m4;
  }
}

// ---------------------------------------------------------------------------
// 9) pool-reduce + fc + meta gate + classifier; block per b
__global__ __launch_bounds__(128) void k_final(
    const float* __restrict__ convp,
    const float* __restrict__ cb3, const float* __restrict__ cb4,
    const float* __restrict__ cb5,
    const float* __restrict__ fc_w, const float* __restrict__ fc_b,
    const float* __restrict__ meta_e,
    const float* __restrict__ mp_w1, const float* __restrict__ mp_b1,
    const float* __restrict__ mp_w2, const float* __restrict__ mp_b2,
    const float* __restrict__ cls_w1, const float* __restrict__ cls_b1,
    const float* __restrict__ cls_w2, const float* __restrict__ cls_b2,
    float* __restrict__ out){
  const int b = blockIdx.x;
  const int c = threadIdx.x;
  __shared__ float pooled[384];
  __shared__ float comb[256];
  __shared__ float hcls[128];
  __shared__ float tt[2][64];
  __shared__ float wsc[2];
  for (int idx=c; idx<384; idx+=128){
    int j = idx >> 7, cc2 = idx & 127;
    const float* base = convp + (((size_t)b*3 + j)*4)*CC + cc2;
    float mx = -1e30f;
    for (int ci=0;ci<4;ci++) mx = fmaxf(mx, base[ci*CC]);
    const float* cb = (j==0)?cb3:(j==1)?cb4:cb5;
    pooled[idx] = fmaxf(mx + cb[cc2], 0.f);
  }
  __syncthreads();
  {
    float acc = fc_b[c];
    const float* wr = fc_w + (size_t)c*384;
    for (int i=0;i<384;i++) acc += pooled[i]*wr[i];
    comb[c] = acc;
  }
  if (c < 64){
    for (int m=0;m<2;m++){
      const float* ev = meta_e + ((size_t)m*BB+b)*DD;
      float acc = mp_b1[c];
      const float* wr = mp_w1 + (size_t)c*DD;
      for (int i=0;i<DD;i++) acc += ev[i]*wr[i];
      tt[m][c] = tanhf(acc);
    }
  }
  __syncthreads();
  if (c == 0){
    float s0 = mp_b2[0], s1 = mp_b2[0];
    for (int j=0;j<64;j++){ s0 += tt[0][j]*mp_w2[j]; s1 += tt[1][j]*mp_w2[j]; }
    float mx = fmaxf(s0,s1);
    float e0 = __expf(s0-mx), e1 = __expf(s1-mx);
    wsc[0] = e0/(e0+e1); wsc[1] = e1/(e0+e1);
  }
  __syncthreads();
  comb[128+c] = wsc[0]*meta_e[((size_t)b)*DD + c]
              + wsc[1]*meta_e[((size_t)(BB+b))*DD + c];
  __syncthreads();
  {
    float acc = cls_b1[c];
    const float* wr = cls_w1 + (size_t)c*256;
    for (int i=0;i<256;i++) acc += comb[i]*wr[i];
    hcls[c] = fmaxf(acc, 0.f);
  }
  __syncthreads();
  if (c < 2){
    float acc = cls_b2[c];
    const float* wr = cls_w2 + (size_t)c*DD;
    for (int i=0;i<DD;i++) acc += hcls[i]*wr[i];
    out[b*2 + c] = acc;
  }
}

// ---------------------------------------------------------------------------
extern "C" void kernel_launch(void* const* d_in, const int* in_sizes, int n_in,
                              void* d_out, int out_size, void* d_ws, size_t ws_size,
                              hipStream_t stream){
  const int* news_ids = (const int*)d_in[0];
  const int* nwi      = (const int*)d_in[1];
  const int* ctx_ids  = (const int*)d_in[2];
  const int* nsn_src  = (const int*)d_in[3];
  const int* nsn_end  = (const int*)d_in[4];
  const int* nun_usr  = (const int*)d_in[5];
  const int* nun_end  = (const int*)d_in[6];
  const float* word_table   = (const float*)d_in[7];
  const float* news_table   = (const float*)d_in[8];
  const float* user_table   = (const float*)d_in[9];
  const float* source_table = (const float*)d_in[10];
  const float* wa_in_w  = (const float*)d_in[11];
  const float* wa_in_b  = (const float*)d_in[12];
  const float* wa_out_w = (const float*)d_in[13];
  const float* wa_out_b = (const float*)d_in[14];
  const float* conv_w3 = (const float*)d_in[15];
  const float* conv_b3 = (const float*)d_in[16];
  const float* conv_w4 = (const float*)d_in[17];
  const float* conv_b4 = (const float*)d_in[18];
  const float* conv_w5 = (const float*)d_in[19];
  const float* conv_b5 = (const float*)d_in[20];
  const float* fc_w = (const float*)d_in[21];
  const float* fc_b = (const float*)d_in[22];
  const float* wih0 = (const float*)d_in[23];
  const float* whh0 = (const float*)d_in[24];
  const float* bih0 = (const float*)d_in[25];
  const float* bhh0 = (const float*)d_in[26];
  const float* inw0 = (const float*)d_in[27];
  const float* inb0 = (const float*)d_in[28];
  const float* outw0 = (const float*)d_in[29];
  const float* outb0 = (const float*)d_in[30];
  const float* lng0 = (const float*)d_in[31];
  const float* lnb0 = (const float*)d_in[32];
  const float* wih1 = (const float*)d_in[33];
  const float* whh1 = (const float*)d_in[34];
  const float* bih1 = (const float*)d_in[35];
  const float* bhh1 = (const float*)d_in[36];
  const float* inw1 = (const float*)d_in[37];
  const float* inb1 = (const float*)d_in[38];
  const float* outw1 = (const float*)d_in[39];
  const float* outb1 = (const float*)d_in[40];
  const float* lng1 = (const float*)d_in[41];
  const float* lnb1 = (const float*)d_in[42];
  const float* mp_w1 = (const float*)d_in[43];
  const float* mp_b1 = (const float*)d_in[44];
  const float* mp_w2 = (const float*)d_in[45];
  const float* mp_b2 = (const float*)d_in[46];
  const float* cls_w1 = (const float*)d_in[47];
  const float* cls_b1 = (const float*)d_in[48];
  const float* cls_w2 = (const float*)d_in[49];
  const float* cls_b2 = (const float*)d_in[50];

  // workspace layout
  char* wsb = (char*)d_ws;
  unsigned short* nK = (unsigned short*)wsb;                 // NNN*DD bf16
  unsigned short* nV = nK + (size_t)NNN*DD;                  // NNN*DD bf16
  unsigned short* wb3 = nV + (size_t)NNN*DD;
  unsigned short* wb4 = wb3 + (size_t)CC*DD*3;
  unsigned short* wb5 = wb4 + (size_t)CC*DD*4;
  unsigned short* wgb = wb5 + (size_t)CC*DD*5;               // 4*384*128 bf16
  unsigned short* wab = wgb + (size_t)4*384*DD;              // 512*128 bf16
  unsigned short* wmh = wab + (size_t)512*DD;                // 2*512*128 bf16
  float* qh     = (float*)(wmh + (size_t)2*512*DD);
  unsigned short* o_at = (unsigned short*)(qh + (size_t)BB*LL*DD);   // bf16
  unsigned short* doc  = (unsigned short*)((float*)o_at + (size_t)BB*LL*DD); // bf16
  float* convp  = (float*)doc + (size_t)BB*LL*DD;
  float* enc    = convp + BB*3*4*CC;
  float* meta_e = enc + (size_t)2*BB*SS*DD;
  const size_t need_bytes = (size_t)((char*)(meta_e + 2*BB*DD) - wsb);
  if (ws_size < need_bytes) return;

  const unsigned short* wqb  = wab;                   // rows 0..127 (wq)
  const unsigned short* wkvb = wab + (size_t)128*DD;  // rows 128..383 (wk;wv)
  const unsigned short* wob  = wab + (size_t)384*DD;  // out_w

  k_prep<<<dim3(320), dim3(256), 0, stream>>>(conv_w3, conv_w4, conv_w5,
      wih0, whh0, wih1, whh1, wa_in_w, wa_out_w,
      inw0, outw0, inw1, outw1,
      wb3, wb4, wb5, wgb, wab, wmh);
  k_pq<<<dim3(PQ_PKV + 128), dim3(256), 0, stream>>>(
      news_table, wkvb, wa_in_b, nK, nV,
      word_table, nwi, wqb, qh);
  k_gru<<<dim3(128), dim3(256), 0, stream>>>(news_table, user_table, source_table,
      news_ids, nsn_src, nsn_end, nun_usr, nun_end,
      wgb, bih0, bhh0, bih1, bhh1, enc);
  k_attn<<<dim3(BB*LL/4), dim3(256), 0, stream>>>(qh, nK, nV, ctx_ids, o_at);
  k_fused2<<<dim3(192), dim3(256), 0, stream>>>(o_at, nwi, wob, wa_out_b, doc,
      enc, wmh, inb0, outb0, lng0, lnb0, inb1, outb1, lng1, lnb1, meta_e);
  k_conv<<<dim3(BB*3*4), dim3(256), 0, stream>>>(doc, wb3, wb4, wb5, convp);
  k_final<<<dim3(BB), dim3(128), 0, stream>>>(convp, conv_b3, conv_b4, conv_b5,
      fc_w, fc_b, meta_e, mp_w1, mp_b1, mp_w2, mp_b2,
      cls_w1, cls_b1, cls_w2, cls_b2, (float*)d_out);
}